// Round 3
// baseline (491.015 us; speedup 1.0000x reference)
//
#include <hip/hip_runtime.h>
#include <math.h>

#define DI __device__ __forceinline__

typedef unsigned short u16;
typedef __attribute__((ext_vector_type(8))) u16 u16x8;
typedef __attribute__((ext_vector_type(4))) u16 u16x4;
typedef __attribute__((ext_vector_type(8))) __bf16 bf16x8;
typedef __attribute__((ext_vector_type(4))) float f32x4;

typedef const __attribute__((address_space(1))) unsigned int g_u32;
typedef __attribute__((address_space(3))) unsigned int l_u32;

DI float bf2f(u16 u) {
  unsigned v = ((unsigned)u) << 16;
  float f; __builtin_memcpy(&f, &v, 4); return f;
}
DI u16 f2bf(float f) {
  unsigned u; __builtin_memcpy(&u, &f, 4);
  u += 0x7fff + ((u >> 16) & 1);   // RNE
  return (u16)(u >> 16);
}
DI f32x4 mfma16(bf16x8 a, bf16x8 b, f32x4 c) {
  return __builtin_amdgcn_mfma_f32_16x16x32_bf16(a, b, c, 0, 0, 0);
}
DI void gl16(const void* g, const u16* lds) {   // async global->LDS, 16B/lane
  __builtin_amdgcn_global_load_lds((g_u32*)g, (l_u32*)lds, 16, 0, 0);
}

// ---------------- conversion: fp32 -> bf16 (elementwise) ----------------
__global__ __launch_bounds__(256) void cvt_bf16_k(const float* __restrict__ in,
                                                  u16* __restrict__ out, int n) {
  int i = (blockIdx.x * 256 + threadIdx.x) * 8;
  if (i >= n) return;
  float4 a = *(const float4*)(in + i);
  float4 b = *(const float4*)(in + i + 4);
  u16x8 o;
  o[0] = f2bf(a.x); o[1] = f2bf(a.y); o[2] = f2bf(a.z); o[3] = f2bf(a.w);
  o[4] = f2bf(b.x); o[5] = f2bf(b.y); o[6] = f2bf(b.z); o[7] = f2bf(b.w);
  *(u16x8*)(out + i) = o;
}

// ---------------- conversion: fp32 [K][N] -> bf16 [N][K] (transpose) ----------------
__global__ __launch_bounds__(256) void tcvt_k(const float* __restrict__ in,
                                              u16* __restrict__ out, int K, int N) {
  __shared__ float tile[32][33];
  int n0 = blockIdx.x * 32, k0 = blockIdx.y * 32;
  int tx = threadIdx.x & 31, ty = threadIdx.x >> 5;  // 32 x 8
  #pragma unroll
  for (int i = 0; i < 4; i++) {
    int kr = ty + i * 8;
    tile[kr][tx] = in[(size_t)(k0 + kr) * N + n0 + tx];
  }
  __syncthreads();
  #pragma unroll
  for (int i = 0; i < 4; i++) {
    int nr = ty + i * 8;
    out[(size_t)(n0 + nr) * K + k0 + tx] = f2bf(tile[tx][nr]);
  }
}

__global__ __launch_bounds__(256) void pack_bias_k(const float* __restrict__ b0,
                                                   const float* __restrict__ b1,
                                                   const float* __restrict__ b2,
                                                   float* __restrict__ out) {
  int i = blockIdx.x * 256 + threadIdx.x;   // grid 12 -> 3072
  float v = (i < 1024) ? b0[i] : (i < 2048 ? b1[i - 1024] : b2[i - 2048]);
  out[i] = v;
}

// ---------------- GEMM: C[M,N] = A[M,K](bf16) @ Bt[N,K](bf16)^T + bias, epilogue ----------------
// 128x128 tile, BK=64, 4 waves; 2-phase double-buffered global_load_lds staging (T3-min);
// bijective XCD-chunked block swizzle + 8-col band traversal (T1).
// EPI 0: out = bf16(acc + bias)
// EPI 1: out = bf16(acc + bias + f32resid)
// EPI 2: out = bf16(gelu_exact(acc + bias))
// EPI 3: out = bf16(acc + bias + bf16resid)
template<int EPI>
__global__ __launch_bounds__(256) void gemm_bt_k(const u16* __restrict__ A,
                                                 const u16* __restrict__ Bt,
                                                 const float* __restrict__ bias,
                                                 const void* __restrict__ resid,
                                                 u16* __restrict__ out,
                                                 int M, int N, int K) {
  __shared__ __align__(16) u16 As[2][128 * 64];
  __shared__ __align__(16) u16 Bs[2][128 * 64];
  const int tid = threadIdx.x;
  const int lane = tid & 63, wid = tid >> 6;
  const int wm = (wid >> 1) * 64, wn = (wid & 1) * 64;
  const int r15 = lane & 15, kg = lane >> 4;
  const int srow = lane >> 3;
  const int scolb = (lane & 7) << 4;

  // ---- T1: bijective XCD swizzle (m204) + 2D band traversal ----
  const int GX = gridDim.x, GY = gridDim.y;
  int nwg = GX * GY;
  int orig = blockIdx.y * GX + blockIdx.x;
  int q = nwg >> 3, r = nwg & 7;
  int xcd = orig & 7, idx = orig >> 3;
  int s = (xcd < r ? xcd * (q + 1) : r * (q + 1) + (xcd - r) * q) + idx;
  int CG = (GX >= 8) ? 8 : GX;           // cols per band (divides all our GX)
  int band = GY * CG;
  int g = s / band, rem = s - g * band;
  int by = rem / CG;
  int bx = g * CG + (rem - by * CG);
  const int bm = by * 128, bn = bx * 128;

  f32x4 acc[4][4];
  #pragma unroll
  for (int i = 0; i < 4; i++)
    #pragma unroll
    for (int j = 0; j < 4; j++) acc[i][j] = (f32x4){0.f, 0.f, 0.f, 0.f};

  // staging: 16 chunks of 1024B per matrix; wave wid takes chunks c*4+wid.
  // chunk ci covers rows [ci*8, ci*8+8); HW writes lane l at chunkbase + l*16.
  auto STAGE = [&](int buf, int kt) {
    #pragma unroll
    for (int c = 0; c < 4; c++) {
      int chunk = (c << 2) | wid;
      int row = (chunk << 3) + srow;
      gl16((const char*)A + ((size_t)(bm + row) * K + kt) * 2 + scolb,
           &As[buf][chunk << 9]);
      gl16((const char*)Bt + ((size_t)(bn + row) * K + kt) * 2 + scolb,
           &Bs[buf][chunk << 9]);
    }
  };
  auto COMPUTE = [&](int buf) {
    #pragma unroll
    for (int ks = 0; ks < 2; ks++) {
      bf16x8 af[4], bfr[4];
      #pragma unroll
      for (int i = 0; i < 4; i++)
        af[i] = *(const bf16x8*)&As[buf][(wm + i * 16 + r15) * 64 + ks * 32 + kg * 8];
      #pragma unroll
      for (int i = 0; i < 4; i++)
        bfr[i] = *(const bf16x8*)&Bs[buf][(wn + i * 16 + r15) * 64 + ks * 32 + kg * 8];
      #pragma unroll
      for (int i = 0; i < 4; i++)
        #pragma unroll
        for (int j = 0; j < 4; j++)
          acc[i][j] = mfma16(af[i], bfr[j], acc[i][j]);
    }
  };

  const int nt = K >> 6;
  STAGE(0, 0);
  __syncthreads();
  int cur = 0;
  for (int t = 0; t + 1 < nt; ++t) {
    STAGE(cur ^ 1, (t + 1) << 6);   // prefetch next K-tile (stays in flight under MFMA)
    COMPUTE(cur);
    __syncthreads();                // drains vmcnt+lgkm, then barrier
    cur ^= 1;
  }
  COMPUTE(cur);                     // last tile, no further staging

  #pragma unroll
  for (int i = 0; i < 4; i++) {
    int row0 = bm + wm + i * 16 + kg * 4;
    #pragma unroll
    for (int j = 0; j < 4; j++) {
      int col = bn + wn + j * 16 + r15;
      float bv = bias[col];
      #pragma unroll
      for (int q2 = 0; q2 < 4; q2++) {
        int row = row0 + q2;
        float v = acc[i][j][q2] + bv;
        if (EPI == 1) v += ((const float*)resid)[(size_t)row * N + col];
        if (EPI == 2) v = 0.5f * v * (1.0f + erff(v * 0.70710678118f));
        if (EPI == 3) v += bf2f(((const u16*)resid)[(size_t)row * N + col]);
        out[(size_t)row * N + col] = f2bf(v);
      }
    }
  }
}

// ---------------- fused attention: per (32-row q-block, head, batch) ----------------
// QKV: bf16 [B*S][3072]; Q at col h*64, K at 1024+h*64, V at 2048+h*64. ctx: [B*S][1024] bf16.
__global__ __launch_bounds__(256) void attn_k(const u16* __restrict__ QKV,
                                              const float* __restrict__ mask,
                                              u16* __restrict__ ctx) {
  __shared__ __align__(16) u16 sQ[32 * 72];
  __shared__ __align__(16) u16 sK[64 * 72];
  __shared__ __align__(16) u16 sVt[64 * 72];     // transposed: sVt[d][kpos]
  __shared__ __align__(16) u16 sS[32 * 520];     // scores then unnormalized probs
  __shared__ float sSum[32];
  const int t = threadIdx.x, lane = t & 63, wid = t >> 6;
  const int qb = blockIdx.x, h = blockIdx.y, b = blockIdx.z;
  const int r15 = lane & 15, kg = lane >> 4;
  const int mg = wid >> 1, half = wid & 1;
  const size_t qoff = (size_t)h * 64;
  const size_t koff = 1024 + qoff, voff = 2048 + qoff;

  {  // stage Q block (32 x 64)
    int row = t >> 3, d0 = (t & 7) * 8;
    *(u16x8*)&sQ[row * 72 + d0] =
        *(const u16x8*)&QKV[((size_t)(b * 512 + qb * 32 + row)) * 3072 + qoff + d0];
  }

  // ---- phase A: S = Q K^T / 8 + mask ----
  for (int kt = 0; kt < 8; ++kt) {
    int row = t >> 2, d0 = (t & 3) * 16;
    const u16* src = &QKV[((size_t)(b * 512 + kt * 64 + row)) * 3072 + koff + d0];
    *(u16x8*)&sK[row * 72 + d0] = *(const u16x8*)src;
    *(u16x8*)&sK[row * 72 + d0 + 8] = *(const u16x8*)(src + 8);
    __syncthreads();
    bf16x8 qf0 = *(const bf16x8*)&sQ[(mg * 16 + r15) * 72 + kg * 8];
    bf16x8 qf1 = *(const bf16x8*)&sQ[(mg * 16 + r15) * 72 + 32 + kg * 8];
    #pragma unroll
    for (int n2 = 0; n2 < 2; n2++) {
      int nt = half * 2 + n2;
      f32x4 sacc = (f32x4){0.f, 0.f, 0.f, 0.f};
      sacc = mfma16(qf0, *(const bf16x8*)&sK[(nt * 16 + r15) * 72 + kg * 8], sacc);
      sacc = mfma16(qf1, *(const bf16x8*)&sK[(nt * 16 + r15) * 72 + 32 + kg * 8], sacc);
      int col = kt * 64 + nt * 16 + r15;
      float mv = mask[b * 512 + col];
      #pragma unroll
      for (int q = 0; q < 4; q++) {
        int rl = mg * 16 + kg * 4 + q;
        sS[rl * 520 + col] = f2bf(sacc[q] * 0.125f + mv);
      }
    }
    __syncthreads();
  }

  // ---- phase B: row softmax (unnormalized; divide at the end) ----
  {
    int row = t >> 3, seg = t & 7;
    float mx = -1e30f;
    for (int j = 0; j < 64; j++)
      mx = fmaxf(mx, bf2f(sS[row * 520 + seg * 64 + j]));
    mx = fmaxf(mx, __shfl_xor(mx, 1));
    mx = fmaxf(mx, __shfl_xor(mx, 2));
    mx = fmaxf(mx, __shfl_xor(mx, 4));
    float sum = 0.f;
    for (int j = 0; j < 64; j++) {
      int idx = row * 520 + seg * 64 + j;
      float p = __expf(bf2f(sS[idx]) - mx);
      sum += p;
      sS[idx] = f2bf(p);
    }
    sum += __shfl_xor(sum, 1);
    sum += __shfl_xor(sum, 2);
    sum += __shfl_xor(sum, 4);
    if (seg == 0) sSum[row] = sum;
  }
  __syncthreads();

  // ---- phase C: ctx = P V ----
  f32x4 pacc[2];
  pacc[0] = (f32x4){0.f, 0.f, 0.f, 0.f};
  pacc[1] = (f32x4){0.f, 0.f, 0.f, 0.f};
  for (int vt = 0; vt < 8; ++vt) {
    int rowk = t >> 2, d0 = (t & 3) * 16;
    const u16* src = &QKV[((size_t)(b * 512 + vt * 64 + rowk)) * 3072 + voff + d0];
    u16x8 v0 = *(const u16x8*)src;
    u16x8 v1 = *(const u16x8*)(src + 8);
    #pragma unroll
    for (int e = 0; e < 8; e++) {
      sVt[(d0 + e) * 72 + rowk] = v0[e];
      sVt[(d0 + 8 + e) * 72 + rowk] = v1[e];
    }
    __syncthreads();
    bf16x8 pf0 = *(const bf16x8*)&sS[(mg * 16 + r15) * 520 + vt * 64 + kg * 8];
    bf16x8 pf1 = *(const bf16x8*)&sS[(mg * 16 + r15) * 520 + vt * 64 + 32 + kg * 8];
    #pragma unroll
    for (int n2 = 0; n2 < 2; n2++) {
      int dcol = half * 32 + n2 * 16;
      pacc[n2] = mfma16(pf0, *(const bf16x8*)&sVt[(dcol + r15) * 72 + kg * 8], pacc[n2]);
      pacc[n2] = mfma16(pf1, *(const bf16x8*)&sVt[(dcol + r15) * 72 + 32 + kg * 8], pacc[n2]);
    }
    __syncthreads();
  }
  #pragma unroll
  for (int n2 = 0; n2 < 2; n2++) {
    int d = half * 32 + n2 * 16 + r15;
    #pragma unroll
    for (int q = 0; q < 4; q++) {
      int rl = mg * 16 + kg * 4 + q;
      float v = pacc[n2][q] / sSum[rl];
      ctx[((size_t)(b * 512 + qb * 32 + rl)) * 1024 + qoff + d] = f2bf(v);
    }
  }
}

// ---------------- LayerNorm over rows of 1024 ----------------
template<int OUTF32>
__global__ __launch_bounds__(256) void ln_k(const u16* __restrict__ in,
                                            const float* __restrict__ g,
                                            const float* __restrict__ be,
                                            void* __restrict__ out) {
  int row = blockIdx.x, t = threadIdx.x;
  const u16* rp = in + (size_t)row * 1024 + t * 4;
  u16x4 raw = *(const u16x4*)rp;
  float x[4];
  #pragma unroll
  for (int i = 0; i < 4; i++) x[i] = bf2f(raw[i]);
  float s = x[0] + x[1] + x[2] + x[3];
  float q = x[0]*x[0] + x[1]*x[1] + x[2]*x[2] + x[3]*x[3];
  #pragma unroll
  for (int off = 32; off; off >>= 1) {
    s += __shfl_down(s, off);
    q += __shfl_down(q, off);
  }
  __shared__ float rs_[4], rq_[4];
  int wid = t >> 6, lane = t & 63;
  if (!lane) { rs_[wid] = s; rq_[wid] = q; }
  __syncthreads();
  float S1 = rs_[0] + rs_[1] + rs_[2] + rs_[3];
  float S2 = rq_[0] + rq_[1] + rq_[2] + rq_[3];
  float mu = S1 * (1.0f / 1024.0f);
  float inv = rsqrtf(S2 * (1.0f / 1024.0f) - mu * mu + 1e-5f);
  #pragma unroll
  for (int i = 0; i < 4; i++) {
    int c = t * 4 + i;
    float y = (x[i] - mu) * inv * g[c] + be[c];
    if (OUTF32) ((float*)out)[(size_t)row * 1024 + c] = y;
    else        ((u16*)out)[(size_t)row * 1024 + c] = f2bf(y);
  }
}

// ---------------- launch ----------------
extern "C" void kernel_launch(void* const* d_in, const int* in_sizes, int n_in,
                              void* d_out, int out_size, void* d_ws, size_t ws_size,
                              hipStream_t stream) {
  const float* hidden = (const float*)d_in[0];
  const float* mask   = (const float*)d_in[1];
  const float* wq  = (const float*)d_in[2];  const float* bq  = (const float*)d_in[3];
  const float* wk  = (const float*)d_in[4];  const float* bk  = (const float*)d_in[5];
  const float* wv  = (const float*)d_in[6];  const float* bv  = (const float*)d_in[7];
  const float* wo  = (const float*)d_in[8];  const float* bo  = (const float*)d_in[9];
  const float* ln1g = (const float*)d_in[10]; const float* ln1b = (const float*)d_in[11];
  const float* wi  = (const float*)d_in[12]; const float* bi  = (const float*)d_in[13];
  const float* wo2 = (const float*)d_in[14]; const float* bo2 = (const float*)d_in[15];
  const float* ln2g = (const float*)d_in[16]; const float* ln2b = (const float*)d_in[17];

  char* ws = (char*)d_ws;
  size_t off = 0;
  auto alloc = [&](size_t elems) -> u16* {
    u16* p = (u16*)(ws + off);
    off += ((elems * 2 + 255) & ~(size_t)255);
    return p;
  };
  u16* Xb    = alloc(4194304);    // [4096][1024] bf16
  u16* WqkvT = alloc(3145728);    // [3072][1024] bf16 (wq^T | wk^T | wv^T)
  u16* WoT   = alloc(1048576);
  u16* WiT   = alloc(4194304);
  u16* Wo2T  = alloc(4194304);
  u16* QKVb  = alloc(12582912);   // [4096][3072] bf16
  u16* Ctx   = alloc(4194304);
  u16* AD    = alloc(4194304);
  u16* AO    = alloc(4194304);
  u16* Inter = alloc(16777216);
  u16* FD    = alloc(4194304);
  float* bqkv = (float*)(ws + off); off += 3072 * 4;

  cvt_bf16_k<<<2048, 256, 0, stream>>>(hidden, Xb, 4194304);
  tcvt_k<<<dim3(32, 32),  256, 0, stream>>>(wq,  WqkvT,                1024, 1024);
  tcvt_k<<<dim3(32, 32),  256, 0, stream>>>(wk,  WqkvT + 1024 * 1024,  1024, 1024);
  tcvt_k<<<dim3(32, 32),  256, 0, stream>>>(wv,  WqkvT + 2048 * 1024,  1024, 1024);
  tcvt_k<<<dim3(32, 32),  256, 0, stream>>>(wo,  WoT,  1024, 1024);
  tcvt_k<<<dim3(128, 32), 256, 0, stream>>>(wi,  WiT,  1024, 4096);
  tcvt_k<<<dim3(32, 128), 256, 0, stream>>>(wo2, Wo2T, 4096, 1024);
  pack_bias_k<<<12, 256, 0, stream>>>(bq, bk, bv, bqkv);

  // fused QKV projection: [4096,1024] @ [1024,3072] -> [4096,3072]
  gemm_bt_k<0><<<dim3(24, 32), 256, 0, stream>>>(Xb, WqkvT, bqkv, nullptr, QKVb, 4096, 3072, 1024);

  attn_k<<<dim3(16, 16, 8), 256, 0, stream>>>(QKVb, mask, Ctx);

  gemm_bt_k<1><<<dim3(8, 32), 256, 0, stream>>>(Ctx, WoT, bo, hidden, AD, 4096, 1024, 1024);
  ln_k<0><<<4096, 256, 0, stream>>>(AD, ln1g, ln1b, AO);
  gemm_bt_k<2><<<dim3(32, 32), 256, 0, stream>>>(AO, WiT, bi, nullptr, Inter, 4096, 4096, 1024);
  gemm_bt_k<3><<<dim3(8, 32), 256, 0, stream>>>(Inter, Wo2T, bo2, AO, FD, 4096, 1024, 4096);
  ln_k<1><<<4096, 256, 0, stream>>>(FD, ln2g, ln2b, d_out);
}

// Round 4
// 433.622 us; speedup vs baseline: 1.1324x; 1.1324x over previous
//
#include <hip/hip_runtime.h>
#include <math.h>

#define DI __device__ __forceinline__

typedef unsigned short u16;
typedef __attribute__((ext_vector_type(8))) u16 u16x8;
typedef __attribute__((ext_vector_type(4))) u16 u16x4;
typedef __attribute__((ext_vector_type(8))) __bf16 bf16x8;
typedef __attribute__((ext_vector_type(4))) float f32x4;

typedef const __attribute__((address_space(1))) unsigned int g_u32;
typedef __attribute__((address_space(3))) unsigned int l_u32;

DI float bf2f(u16 u) {
  unsigned v = ((unsigned)u) << 16;
  float f; __builtin_memcpy(&f, &v, 4); return f;
}
DI u16 f2bf(float f) {
  unsigned u; __builtin_memcpy(&u, &f, 4);
  u += 0x7fff + ((u >> 16) & 1);   // RNE
  return (u16)(u >> 16);
}
DI f32x4 mfma16(bf16x8 a, bf16x8 b, f32x4 c) {
  return __builtin_amdgcn_mfma_f32_16x16x32_bf16(a, b, c, 0, 0, 0);
}
DI void gl16(const void* g, const u16* lds) {   // async global->LDS, 16B/lane
  __builtin_amdgcn_global_load_lds((g_u32*)g, (l_u32*)lds, 16, 0, 0);
}

// ---------------- conversion: fp32 -> bf16 (elementwise) ----------------
__global__ __launch_bounds__(256) void cvt_bf16_k(const float* __restrict__ in,
                                                  u16* __restrict__ out, int n) {
  int i = (blockIdx.x * 256 + threadIdx.x) * 8;
  if (i >= n) return;
  float4 a = *(const float4*)(in + i);
  float4 b = *(const float4*)(in + i + 4);
  u16x8 o;
  o[0] = f2bf(a.x); o[1] = f2bf(a.y); o[2] = f2bf(a.z); o[3] = f2bf(a.w);
  o[4] = f2bf(b.x); o[5] = f2bf(b.y); o[6] = f2bf(b.z); o[7] = f2bf(b.w);
  *(u16x8*)(out + i) = o;
}

// ---------------- conversion: fp32 [K][N] -> bf16 [N][K] (transpose) ----------------
__global__ __launch_bounds__(256) void tcvt_k(const float* __restrict__ in,
                                              u16* __restrict__ out, int K, int N) {
  __shared__ float tile[32][33];
  int n0 = blockIdx.x * 32, k0 = blockIdx.y * 32;
  int tx = threadIdx.x & 31, ty = threadIdx.x >> 5;  // 32 x 8
  #pragma unroll
  for (int i = 0; i < 4; i++) {
    int kr = ty + i * 8;
    tile[kr][tx] = in[(size_t)(k0 + kr) * N + n0 + tx];
  }
  __syncthreads();
  #pragma unroll
  for (int i = 0; i < 4; i++) {
    int nr = ty + i * 8;
    out[(size_t)(n0 + nr) * K + k0 + tx] = f2bf(tile[tx][nr]);
  }
}

__global__ __launch_bounds__(256) void pack_bias_k(const float* __restrict__ b0,
                                                   const float* __restrict__ b1,
                                                   const float* __restrict__ b2,
                                                   float* __restrict__ out) {
  int i = blockIdx.x * 256 + threadIdx.x;   // grid 12 -> 3072
  float v = (i < 1024) ? b0[i] : (i < 2048 ? b1[i - 1024] : b2[i - 2048]);
  out[i] = v;
}

// ================= 256x256 8-phase GEMM (T1+T2+T3+T4+T5) =================
// C[M,N] = A[M,K] @ Bt[N,K]^T (+ optional split-K partials)
// 8 waves (2M x 4N), wave tile 128x64, BK=64, LDS 128KB (2 dbuf x 2 half x [128][64] x {A,B}).
// T2: 16B slot s of row r stored at slot (s+r)&7  -> ds_read 2-way (free), gl16 dest linear,
//     global source inverse-permuted (rule 21: both-sides-or-neither).
// EPI 0: bf16(acc+bias) | EPI 2: bf16(gelu(acc+bias)) | EPI 4: fp32 partial (no bias)
#define QUAD(d, mh, nh) do {                                                          \
  const u16* Ab_ = &sA[d][wr][0];                                                     \
  const u16* Bb_ = &sB[d][wc >> 1][0];                                                \
  bf16x8 af_[4][2], bv_[2][2];                                                        \
  _Pragma("unroll") for (int i_ = 0; i_ < 4; i_++) {                                  \
    int row_ = (mh) * 64 + i_ * 16 + r15;                                             \
    _Pragma("unroll") for (int ks_ = 0; ks_ < 2; ks_++)                               \
      af_[i_][ks_] = *(const bf16x8*)&Ab_[row_ * 64 + ((((ks_ << 2) | kg) + row_) & 7) * 8]; } \
  _Pragma("unroll") for (int j_ = 0; j_ < 2; j_++) {                                  \
    int row_ = (wc & 1) * 64 + (nh) * 32 + j_ * 16 + r15;                             \
    _Pragma("unroll") for (int ks_ = 0; ks_ < 2; ks_++)                               \
      bv_[j_][ks_] = *(const bf16x8*)&Bb_[row_ * 64 + ((((ks_ << 2) | kg) + row_) & 7) * 8]; } \
  __builtin_amdgcn_s_barrier();                                                       \
  __builtin_amdgcn_s_setprio(1);                                                      \
  _Pragma("unroll") for (int i_ = 0; i_ < 4; i_++)                                    \
    _Pragma("unroll") for (int j_ = 0; j_ < 2; j_++)                                  \
      _Pragma("unroll") for (int ks_ = 0; ks_ < 2; ks_++)                             \
        acc[(mh) * 4 + i_][(nh) * 2 + j_] =                                           \
            mfma16(af_[i_][ks_], bv_[j_][ks_], acc[(mh) * 4 + i_][(nh) * 2 + j_]);    \
  __builtin_amdgcn_s_setprio(0);                                                      \
} while (0)

template<int EPI, int SPLITK>
__global__ __launch_bounds__(512, 2) void gemm8p_k(const u16* __restrict__ A,
                                                   const u16* __restrict__ Bt,
                                                   const float* __restrict__ bias,
                                                   void* __restrict__ out,
                                                   int M, int N, int K) {
  __shared__ __align__(16) u16 sA[2][2][128 * 64];
  __shared__ __align__(16) u16 sB[2][2][128 * 64];
  const int tid = threadIdx.x;
  const int lane = tid & 63, wid = tid >> 6;
  const int wr = wid >> 2, wc = wid & 3;          // 2 x 4 waves
  const int r15 = lane & 15, kg = lane >> 4;

  // T1: bijective XCD swizzle + column-major chunking (nwg % 8 == 0 for all our grids)
  const int GX = gridDim.x, GY = gridDim.y;
  int nwg = GX * GY;
  int orig = blockIdx.y * GX + blockIdx.x;
  int s = (orig & 7) * (nwg >> 3) + (orig >> 3);
  int bx = s / GY, by = s - bx * GY;
  const int bm = by * 256, bn = bx * 256;

  // split-K range
  const int z = blockIdx.z;
  int tilesK = K >> 6;
  int qs = tilesK / SPLITK, rs = tilesK - qs * SPLITK;
  int ntz = qs + (z < rs ? 1 : 0);
  int k0 = (z * qs + (z < rs ? z : rs)) << 6;

  f32x4 acc[8][4];
  #pragma unroll
  for (int i = 0; i < 8; i++)
    #pragma unroll
    for (int j = 0; j < 4; j++) acc[i][j] = (f32x4){0.f, 0.f, 0.f, 0.f};

  // stage one 128x64 half-tile: linear LDS dest, inverse-rotated global source
  auto stageHalf = [&](const u16* __restrict__ X, int grow0, int kcol, u16* dst) {
    #pragma unroll
    for (int s2 = 0; s2 < 2; s2++) {
      int idx = (s2 << 9) | tid;           // 0..1023 -> 16B chunk index
      int drow = idx >> 3;
      int gslot = (idx - drow) & 7;        // (dslot - drow) & 7
      gl16(X + (size_t)(grow0 + drow) * K + kcol + (gslot << 3),
           dst + (((s2 << 9) | (wid << 6)) << 3));
    }
  };

  // prologue: stage K-tile 0 into dbuf 0
  stageHalf(A,  bm,       k0, &sA[0][0][0]);
  stageHalf(Bt, bn,       k0, &sB[0][0][0]);
  stageHalf(A,  bm + 128, k0, &sA[0][1][0]);
  stageHalf(Bt, bn + 128, k0, &sB[0][1][0]);

  for (int t = 0; t < ntz; ++t) {
    int d = t & 1;
    asm volatile("s_waitcnt vmcnt(0)" ::: "memory");   // my tile-t stages landed
    __builtin_amdgcn_s_barrier();                      // everyone's landed; other dbuf free
    const bool pf = (t + 1 < ntz);
    const int kn = k0 + ((t + 1) << 6);
    if (pf) { stageHalf(A, bm,        kn, &sA[d ^ 1][0][0]);
              stageHalf(Bt, bn,       kn, &sB[d ^ 1][0][0]); }
    QUAD(d, 0, 0);
    if (pf) { stageHalf(A, bm + 128,  kn, &sA[d ^ 1][1][0]);
              stageHalf(Bt, bn + 128, kn, &sB[d ^ 1][1][0]); }
    QUAD(d, 0, 1);
    QUAD(d, 1, 0);
    QUAD(d, 1, 1);
    asm volatile("s_waitcnt lgkmcnt(0)" ::: "memory"); // my LDS reads of dbuf d complete
    __builtin_amdgcn_sched_barrier(0);
  }

  // epilogue
  #pragma unroll
  for (int ii = 0; ii < 8; ii++) {
    int row = bm + wr * 128 + ii * 16 + kg * 4;
    #pragma unroll
    for (int jj = 0; jj < 4; jj++) {
      int col = bn + wc * 64 + jj * 16 + r15;
      if (EPI == 4) {
        size_t zoff = (size_t)z * M * N;
        #pragma unroll
        for (int q2 = 0; q2 < 4; q2++)
          ((float*)out)[zoff + (size_t)(row + q2) * N + col] = acc[ii][jj][q2];
      } else {
        float bv = bias[col];
        #pragma unroll
        for (int q2 = 0; q2 < 4; q2++) {
          float v = acc[ii][jj][q2] + bv;
          if (EPI == 2) v = 0.5f * v * (1.0f + erff(v * 0.70710678118f));
          ((u16*)out)[(size_t)(row + q2) * N + col] = f2bf(v);
        }
      }
    }
  }
}

// ---------------- 128x128 2-phase GEMM (kept for attn-dense) ----------------
// EPI 1: out = bf16(acc + bias + f32resid)
template<int EPI>
__global__ __launch_bounds__(256) void gemm_bt_k(const u16* __restrict__ A,
                                                 const u16* __restrict__ Bt,
                                                 const float* __restrict__ bias,
                                                 const void* __restrict__ resid,
                                                 u16* __restrict__ out,
                                                 int M, int N, int K) {
  __shared__ __align__(16) u16 As[2][128 * 64];
  __shared__ __align__(16) u16 Bs[2][128 * 64];
  const int tid = threadIdx.x;
  const int lane = tid & 63, wid = tid >> 6;
  const int wm = (wid >> 1) * 64, wn = (wid & 1) * 64;
  const int r15 = lane & 15, kg = lane >> 4;
  const int srow = lane >> 3;
  const int scolb = (lane & 7) << 4;

  const int GX = gridDim.x, GY = gridDim.y;
  int nwg = GX * GY;
  int orig = blockIdx.y * GX + blockIdx.x;
  int s = (orig & 7) * (nwg >> 3) + (orig >> 3);
  int bx = s / GY, by = s - bx * GY;
  const int bm = by * 128, bn = bx * 128;

  f32x4 acc[4][4];
  #pragma unroll
  for (int i = 0; i < 4; i++)
    #pragma unroll
    for (int j = 0; j < 4; j++) acc[i][j] = (f32x4){0.f, 0.f, 0.f, 0.f};

  auto STAGE = [&](int buf, int kt) {
    #pragma unroll
    for (int c = 0; c < 4; c++) {
      int chunk = (c << 2) | wid;
      int row = (chunk << 3) + srow;
      gl16((const char*)A + ((size_t)(bm + row) * K + kt) * 2 + scolb,
           &As[buf][chunk << 9]);
      gl16((const char*)Bt + ((size_t)(bn + row) * K + kt) * 2 + scolb,
           &Bs[buf][chunk << 9]);
    }
  };
  auto COMPUTE = [&](int buf) {
    #pragma unroll
    for (int ks = 0; ks < 2; ks++) {
      bf16x8 af[4], bfr[4];
      #pragma unroll
      for (int i = 0; i < 4; i++)
        af[i] = *(const bf16x8*)&As[buf][(wm + i * 16 + r15) * 64 + ks * 32 + kg * 8];
      #pragma unroll
      for (int i = 0; i < 4; i++)
        bfr[i] = *(const bf16x8*)&Bs[buf][(wn + i * 16 + r15) * 64 + ks * 32 + kg * 8];
      #pragma unroll
      for (int i = 0; i < 4; i++)
        #pragma unroll
        for (int j = 0; j < 4; j++)
          acc[i][j] = mfma16(af[i], bfr[j], acc[i][j]);
    }
  };

  const int nt = K >> 6;
  STAGE(0, 0);
  __syncthreads();
  int cur = 0;
  for (int t = 0; t + 1 < nt; ++t) {
    STAGE(cur ^ 1, (t + 1) << 6);
    COMPUTE(cur);
    __syncthreads();
    cur ^= 1;
  }
  COMPUTE(cur);

  #pragma unroll
  for (int i = 0; i < 4; i++) {
    int row0 = bm + wm + i * 16 + kg * 4;
    #pragma unroll
    for (int j = 0; j < 4; j++) {
      int col = bn + wn + j * 16 + r15;
      float bv = bias[col];
      #pragma unroll
      for (int q2 = 0; q2 < 4; q2++) {
        int row = row0 + q2;
        float v = acc[i][j][q2] + bv;
        if (EPI == 1) v += ((const float*)resid)[(size_t)row * N + col];
        out[(size_t)row * N + col] = f2bf(v);
      }
    }
  }
}

// ---------------- fused attention: per (32-row q-block, head, batch) ----------------
__global__ __launch_bounds__(256) void attn_k(const u16* __restrict__ QKV,
                                              const float* __restrict__ mask,
                                              u16* __restrict__ ctx) {
  __shared__ __align__(16) u16 sQ[32 * 72];
  __shared__ __align__(16) u16 sK[64 * 72];
  __shared__ __align__(16) u16 sVt[64 * 72];
  __shared__ __align__(16) u16 sS[32 * 520];
  __shared__ float sSum[32];
  const int t = threadIdx.x, lane = t & 63, wid = t >> 6;
  const int qb = blockIdx.x, h = blockIdx.y, b = blockIdx.z;
  const int r15 = lane & 15, kg = lane >> 4;
  const int mg = wid >> 1, half = wid & 1;
  const size_t qoff = (size_t)h * 64;
  const size_t koff = 1024 + qoff, voff = 2048 + qoff;

  {  // stage Q block (32 x 64)
    int row = t >> 3, d0 = (t & 7) * 8;
    *(u16x8*)&sQ[row * 72 + d0] =
        *(const u16x8*)&QKV[((size_t)(b * 512 + qb * 32 + row)) * 3072 + qoff + d0];
  }

  for (int kt = 0; kt < 8; ++kt) {
    int row = t >> 2, d0 = (t & 3) * 16;
    const u16* src = &QKV[((size_t)(b * 512 + kt * 64 + row)) * 3072 + koff + d0];
    *(u16x8*)&sK[row * 72 + d0] = *(const u16x8*)src;
    *(u16x8*)&sK[row * 72 + d0 + 8] = *(const u16x8*)(src + 8);
    __syncthreads();
    bf16x8 qf0 = *(const bf16x8*)&sQ[(mg * 16 + r15) * 72 + kg * 8];
    bf16x8 qf1 = *(const bf16x8*)&sQ[(mg * 16 + r15) * 72 + 32 + kg * 8];
    #pragma unroll
    for (int n2 = 0; n2 < 2; n2++) {
      int nt = half * 2 + n2;
      f32x4 sacc = (f32x4){0.f, 0.f, 0.f, 0.f};
      sacc = mfma16(qf0, *(const bf16x8*)&sK[(nt * 16 + r15) * 72 + kg * 8], sacc);
      sacc = mfma16(qf1, *(const bf16x8*)&sK[(nt * 16 + r15) * 72 + 32 + kg * 8], sacc);
      int col = kt * 64 + nt * 16 + r15;
      float mv = mask[b * 512 + col];
      #pragma unroll
      for (int q = 0; q < 4; q++) {
        int rl = mg * 16 + kg * 4 + q;
        sS[rl * 520 + col] = f2bf(sacc[q] * 0.125f + mv);
      }
    }
    __syncthreads();
  }

  {
    int row = t >> 3, seg = t & 7;
    float mx = -1e30f;
    for (int j = 0; j < 64; j++)
      mx = fmaxf(mx, bf2f(sS[row * 520 + seg * 64 + j]));
    mx = fmaxf(mx, __shfl_xor(mx, 1));
    mx = fmaxf(mx, __shfl_xor(mx, 2));
    mx = fmaxf(mx, __shfl_xor(mx, 4));
    float sum = 0.f;
    for (int j = 0; j < 64; j++) {
      int idx = row * 520 + seg * 64 + j;
      float p = __expf(bf2f(sS[idx]) - mx);
      sum += p;
      sS[idx] = f2bf(p);
    }
    sum += __shfl_xor(sum, 1);
    sum += __shfl_xor(sum, 2);
    sum += __shfl_xor(sum, 4);
    if (seg == 0) sSum[row] = sum;
  }
  __syncthreads();

  f32x4 pacc[2];
  pacc[0] = (f32x4){0.f, 0.f, 0.f, 0.f};
  pacc[1] = (f32x4){0.f, 0.f, 0.f, 0.f};
  for (int vt = 0; vt < 8; ++vt) {
    int rowk = t >> 2, d0 = (t & 3) * 16;
    const u16* src = &QKV[((size_t)(b * 512 + vt * 64 + rowk)) * 3072 + voff + d0];
    u16x8 v0 = *(const u16x8*)src;
    u16x8 v1 = *(const u16x8*)(src + 8);
    #pragma unroll
    for (int e = 0; e < 8; e++) {
      sVt[(d0 + e) * 72 + rowk] = v0[e];
      sVt[(d0 + 8 + e) * 72 + rowk] = v1[e];
    }
    __syncthreads();
    bf16x8 pf0 = *(const bf16x8*)&sS[(mg * 16 + r15) * 520 + vt * 64 + kg * 8];
    bf16x8 pf1 = *(const bf16x8*)&sS[(mg * 16 + r15) * 520 + vt * 64 + 32 + kg * 8];
    #pragma unroll
    for (int n2 = 0; n2 < 2; n2++) {
      int dcol = half * 32 + n2 * 16;
      pacc[n2] = mfma16(pf0, *(const bf16x8*)&sVt[(dcol + r15) * 72 + kg * 8], pacc[n2]);
      pacc[n2] = mfma16(pf1, *(const bf16x8*)&sVt[(dcol + r15) * 72 + 32 + kg * 8], pacc[n2]);
    }
    __syncthreads();
  }
  #pragma unroll
  for (int n2 = 0; n2 < 2; n2++) {
    int d = half * 32 + n2 * 16 + r15;
    #pragma unroll
    for (int q = 0; q < 4; q++) {
      int rl = mg * 16 + kg * 4 + q;
      float v = pacc[n2][q] / sSum[rl];
      ctx[((size_t)(b * 512 + qb * 32 + rl)) * 1024 + qoff + d] = f2bf(v);
    }
  }
}

// ---------------- LayerNorm over rows of 1024 ----------------
template<int OUTF32>
__global__ __launch_bounds__(256) void ln_k(const u16* __restrict__ in,
                                            const float* __restrict__ g,
                                            const float* __restrict__ be,
                                            void* __restrict__ out) {
  int row = blockIdx.x, t = threadIdx.x;
  const u16* rp = in + (size_t)row * 1024 + t * 4;
  u16x4 raw = *(const u16x4*)rp;
  float x[4];
  #pragma unroll
  for (int i = 0; i < 4; i++) x[i] = bf2f(raw[i]);
  float s = x[0] + x[1] + x[2] + x[3];
  float q = x[0]*x[0] + x[1]*x[1] + x[2]*x[2] + x[3]*x[3];
  #pragma unroll
  for (int off = 32; off; off >>= 1) {
    s += __shfl_down(s, off);
    q += __shfl_down(q, off);
  }
  __shared__ float rs_[4], rq_[4];
  int wid = t >> 6, lane = t & 63;
  if (!lane) { rs_[wid] = s; rq_[wid] = q; }
  __syncthreads();
  float S1 = rs_[0] + rs_[1] + rs_[2] + rs_[3];
  float S2 = rq_[0] + rq_[1] + rq_[2] + rq_[3];
  float mu = S1 * (1.0f / 1024.0f);
  float inv = rsqrtf(S2 * (1.0f / 1024.0f) - mu * mu + 1e-5f);
  #pragma unroll
  for (int i = 0; i < 4; i++) {
    int c = t * 4 + i;
    float y = (x[i] - mu) * inv * g[c] + be[c];
    if (OUTF32) ((float*)out)[(size_t)row * 1024 + c] = y;
    else        ((u16*)out)[(size_t)row * 1024 + c] = f2bf(y);
  }
}

// ---------------- split-K reduce (3 partials) + bias + bf16 resid + LayerNorm -> fp32 ----------------
__global__ __launch_bounds__(256) void ln2r_k(const float* __restrict__ part,
                                              const float* __restrict__ bias,
                                              const u16* __restrict__ resid,
                                              const float* __restrict__ g,
                                              const float* __restrict__ be,
                                              float* __restrict__ out) {
  const int row = blockIdx.x, t = threadIdx.x;
  const size_t base = (size_t)row * 1024 + t * 4;
  float4 p0 = *(const float4*)(part + base);
  float4 p1 = *(const float4*)(part + 4194304 + base);
  float4 p2 = *(const float4*)(part + 8388608 + base);
  u16x4 rr = *(const u16x4*)(resid + base);
  float x[4];
  x[0] = p0.x + p1.x + p2.x + bias[t*4+0] + bf2f(rr[0]);
  x[1] = p0.y + p1.y + p2.y + bias[t*4+1] + bf2f(rr[1]);
  x[2] = p0.z + p1.z + p2.z + bias[t*4+2] + bf2f(rr[2]);
  x[3] = p0.w + p1.w + p2.w + bias[t*4+3] + bf2f(rr[3]);
  float s = x[0] + x[1] + x[2] + x[3];
  float q = x[0]*x[0] + x[1]*x[1] + x[2]*x[2] + x[3]*x[3];
  #pragma unroll
  for (int off = 32; off; off >>= 1) {
    s += __shfl_down(s, off);
    q += __shfl_down(q, off);
  }
  __shared__ float rs_[4], rq_[4];
  int wid = t >> 6, lane = t & 63;
  if (!lane) { rs_[wid] = s; rq_[wid] = q; }
  __syncthreads();
  float S1 = rs_[0] + rs_[1] + rs_[2] + rs_[3];
  float S2 = rq_[0] + rq_[1] + rq_[2] + rq_[3];
  float mu = S1 * (1.0f / 1024.0f);
  float inv = rsqrtf(S2 * (1.0f / 1024.0f) - mu * mu + 1e-5f);
  #pragma unroll
  for (int i = 0; i < 4; i++) {
    int c = t * 4 + i;
    out[(size_t)row * 1024 + c] = (x[i] - mu) * inv * g[c] + be[c];
  }
}

// ---------------- launch ----------------
extern "C" void kernel_launch(void* const* d_in, const int* in_sizes, int n_in,
                              void* d_out, int out_size, void* d_ws, size_t ws_size,
                              hipStream_t stream) {
  const float* hidden = (const float*)d_in[0];
  const float* mask   = (const float*)d_in[1];
  const float* wq  = (const float*)d_in[2];  const float* bq  = (const float*)d_in[3];
  const float* wk  = (const float*)d_in[4];  const float* bk  = (const float*)d_in[5];
  const float* wv  = (const float*)d_in[6];  const float* bv  = (const float*)d_in[7];
  const float* wo  = (const float*)d_in[8];  const float* bo  = (const float*)d_in[9];
  const float* ln1g = (const float*)d_in[10]; const float* ln1b = (const float*)d_in[11];
  const float* wi  = (const float*)d_in[12]; const float* bi  = (const float*)d_in[13];
  const float* wo2 = (const float*)d_in[14]; const float* bo2 = (const float*)d_in[15];
  const float* ln2g = (const float*)d_in[16]; const float* ln2b = (const float*)d_in[17];

  char* ws = (char*)d_ws;
  // layout (bytes). The front 56MB [WqkvT..AD] is all dead by FFN2 time and is
  // reused as the 48MB fp32 split-K partial buffer (3 x [4096][1024] fp32).
  u16*   WqkvT = (u16*)(ws + 0);                 //  6291456  [3072][1024] bf16
  u16*   WoT   = (u16*)(ws + 6291456);           //  2097152
  u16*   Xb    = (u16*)(ws + 8388608);           //  8388608  [4096][1024]
  u16*   QKVb  = (u16*)(ws + 16777216);          // 25165824  [4096][3072]
  u16*   Ctx   = (u16*)(ws + 41943040);          //  8388608
  u16*   AD    = (u16*)(ws + 50331648);          //  8388608
  float* part  = (float*)(ws + 0);               // 50331648  (overlaps dead region)
  u16*   AO    = (u16*)(ws + 58720256);          //  8388608
  u16*   Inter = (u16*)(ws + 67108864);          // 33554432  [4096][4096]
  u16*   WiT   = (u16*)(ws + 100663296);         //  8388608  [4096][1024]
  u16*   Wo2T  = (u16*)(ws + 109051904);         //  8388608  [1024][4096]
  float* bqkv  = (float*)(ws + 117440512);       //    12288

  cvt_bf16_k<<<2048, 256, 0, stream>>>(hidden, Xb, 4194304);
  tcvt_k<<<dim3(32, 32),  256, 0, stream>>>(wq,  WqkvT,                1024, 1024);
  tcvt_k<<<dim3(32, 32),  256, 0, stream>>>(wk,  WqkvT + 1024 * 1024,  1024, 1024);
  tcvt_k<<<dim3(32, 32),  256, 0, stream>>>(wv,  WqkvT + 2048 * 1024,  1024, 1024);
  tcvt_k<<<dim3(32, 32),  256, 0, stream>>>(wo,  WoT,  1024, 1024);
  tcvt_k<<<dim3(128, 32), 256, 0, stream>>>(wi,  WiT,  1024, 4096);
  tcvt_k<<<dim3(32, 128), 256, 0, stream>>>(wo2, Wo2T, 4096, 1024);
  pack_bias_k<<<12, 256, 0, stream>>>(bq, bk, bv, bqkv);

  // QKV projection: [4096,1024] @ [1024,3072]
  gemm8p_k<0, 1><<<dim3(12, 16, 1), 512, 0, stream>>>(Xb, WqkvT, bqkv, QKVb, 4096, 3072, 1024);

  attn_k<<<dim3(16, 16, 8), 256, 0, stream>>>(QKVb, mask, Ctx);

  // attn out-proj + f32 residual (small GEMM: keep 128^2 kernel, full grid fill)
  gemm_bt_k<1><<<dim3(8, 32), 256, 0, stream>>>(Ctx, WoT, bo, hidden, AD, 4096, 1024, 1024);
  ln_k<0><<<4096, 256, 0, stream>>>(AD, ln1g, ln1b, AO);

  // FFN1 + GELU: [4096,1024] @ [1024,4096]
  gemm8p_k<2, 1><<<dim3(16, 16, 1), 512, 0, stream>>>(AO, WiT, bi, Inter, 4096, 4096, 1024);

  // FFN2 split-K=3 partials: [4096,4096] @ [4096,1024]
  gemm8p_k<4, 3><<<dim3(4, 16, 3), 512, 0, stream>>>(Inter, Wo2T, nullptr, part, 4096, 1024, 4096);

  // reduce partials + bias + residual(AO) + LN2 -> fp32 out
  ln2r_k<<<4096, 256, 0, stream>>>(part, bo2, AO, ln2g, ln2b, (float*)d_out);
}

// Round 5
// 412.036 us; speedup vs baseline: 1.1917x; 1.0524x over previous
//
#include <hip/hip_runtime.h>
#include <math.h>

#define DI __device__ __forceinline__

typedef unsigned short u16;
typedef __attribute__((ext_vector_type(8))) u16 u16x8;
typedef __attribute__((ext_vector_type(4))) u16 u16x4;
typedef __attribute__((ext_vector_type(8))) __bf16 bf16x8;
typedef __attribute__((ext_vector_type(4))) float f32x4;

typedef const __attribute__((address_space(1))) unsigned int g_u32;
typedef __attribute__((address_space(3))) unsigned int l_u32;

DI float bf2f(u16 u) {
  unsigned v = ((unsigned)u) << 16;
  float f; __builtin_memcpy(&f, &v, 4); return f;
}
DI u16 f2bf(float f) {
  unsigned u; __builtin_memcpy(&u, &f, 4);
  u += 0x7fff + ((u >> 16) & 1);   // RNE
  return (u16)(u >> 16);
}
DI f32x4 mfma16(bf16x8 a, bf16x8 b, f32x4 c) {
  return __builtin_amdgcn_mfma_f32_16x16x32_bf16(a, b, c, 0, 0, 0);
}
DI void gl16(const void* g, const u16* lds) {   // async global->LDS, 16B/lane
  __builtin_amdgcn_global_load_lds((g_u32*)g, (l_u32*)lds, 16, 0, 0);
}

// ---------------- conversion: fp32 -> bf16 (elementwise) ----------------
__global__ __launch_bounds__(256) void cvt_bf16_k(const float* __restrict__ in,
                                                  u16* __restrict__ out, int n) {
  int i = (blockIdx.x * 256 + threadIdx.x) * 8;
  if (i >= n) return;
  float4 a = *(const float4*)(in + i);
  float4 b = *(const float4*)(in + i + 4);
  u16x8 o;
  o[0] = f2bf(a.x); o[1] = f2bf(a.y); o[2] = f2bf(a.z); o[3] = f2bf(a.w);
  o[4] = f2bf(b.x); o[5] = f2bf(b.y); o[6] = f2bf(b.z); o[7] = f2bf(b.w);
  *(u16x8*)(out + i) = o;
}

// ---------------- conversion: fp32 [K][N] -> bf16 [N][K] (transpose) ----------------
__global__ __launch_bounds__(256) void tcvt_k(const float* __restrict__ in,
                                              u16* __restrict__ out, int K, int N) {
  __shared__ float tile[32][33];
  int n0 = blockIdx.x * 32, k0 = blockIdx.y * 32;
  int tx = threadIdx.x & 31, ty = threadIdx.x >> 5;  // 32 x 8
  #pragma unroll
  for (int i = 0; i < 4; i++) {
    int kr = ty + i * 8;
    tile[kr][tx] = in[(size_t)(k0 + kr) * N + n0 + tx];
  }
  __syncthreads();
  #pragma unroll
  for (int i = 0; i < 4; i++) {
    int nr = ty + i * 8;
    out[(size_t)(n0 + nr) * K + k0 + tx] = f2bf(tile[tx][nr]);
  }
}

__global__ __launch_bounds__(256) void pack_bias_k(const float* __restrict__ b0,
                                                   const float* __restrict__ b1,
                                                   const float* __restrict__ b2,
                                                   float* __restrict__ out) {
  int i = blockIdx.x * 256 + threadIdx.x;   // grid 12 -> 3072
  float v = (i < 1024) ? b0[i] : (i < 2048 ? b1[i - 1024] : b2[i - 2048]);
  out[i] = v;
}

// ================= 256x256 8-phase GEMM (T1+T2+T3+T4+T5) =================
// C[M,N] = A[M,K] @ Bt[N,K]^T (+ optional split-K partials)
// 8 waves (2M x 4N), wave tile 128x64, BK=64, LDS 128KB (2 dbuf x 2 half x [128][64] x {A,B}).
// T2: 16B slot s of row r stored at slot (s+r)&7 (ds_read 2-way = free); gl16 dest linear,
//     global source inverse-rotated (rule 21).
// T4: counted vmcnt(8) per tile — tile t+1's 8 loads stay in flight across the barrier.
// EPI 0: bf16(acc+bias) | EPI 2: bf16(gelu(acc+bias)) | EPI 4: fp32 partial (no bias)
#define QUAD(d, mh, nh) do {                                                          \
  const u16* Ab_ = &sA[d][wr][0];                                                     \
  const u16* Bb_ = &sB[d][wc >> 1][0];                                                \
  bf16x8 af_[4][2], bv_[2][2];                                                        \
  _Pragma("unroll") for (int i_ = 0; i_ < 4; i_++) {                                  \
    int row_ = (mh) * 64 + i_ * 16 + r15;                                             \
    _Pragma("unroll") for (int ks_ = 0; ks_ < 2; ks_++)                               \
      af_[i_][ks_] = *(const bf16x8*)&Ab_[row_ * 64 + ((((ks_ << 2) | kg) + row_) & 7) * 8]; } \
  _Pragma("unroll") for (int j_ = 0; j_ < 2; j_++) {                                  \
    int row_ = (wc & 1) * 64 + (nh) * 32 + j_ * 16 + r15;                             \
    _Pragma("unroll") for (int ks_ = 0; ks_ < 2; ks_++)                               \
      bv_[j_][ks_] = *(const bf16x8*)&Bb_[row_ * 64 + ((((ks_ << 2) | kg) + row_) & 7) * 8]; } \
  __builtin_amdgcn_s_barrier();                                                       \
  __builtin_amdgcn_s_setprio(1);                                                      \
  _Pragma("unroll") for (int i_ = 0; i_ < 4; i_++)                                    \
    _Pragma("unroll") for (int j_ = 0; j_ < 2; j_++)                                  \
      _Pragma("unroll") for (int ks_ = 0; ks_ < 2; ks_++)                             \
        acc[(mh) * 4 + i_][(nh) * 2 + j_] =                                           \
            mfma16(af_[i_][ks_], bv_[j_][ks_], acc[(mh) * 4 + i_][(nh) * 2 + j_]);    \
  __builtin_amdgcn_s_setprio(0);                                                      \
} while (0)

template<int EPI, int SPLITK>
__global__ __launch_bounds__(512, 2) void gemm8p_k(const u16* __restrict__ A,
                                                   const u16* __restrict__ Bt,
                                                   const float* __restrict__ bias,
                                                   void* __restrict__ out,
                                                   int M, int N, int K) {
  __shared__ __align__(16) u16 sA[2][2][128 * 64];
  __shared__ __align__(16) u16 sB[2][2][128 * 64];
  const int tid = threadIdx.x;
  const int lane = tid & 63, wid = tid >> 6;
  const int wr = wid >> 2, wc = wid & 3;          // 2 x 4 waves
  const int r15 = lane & 15, kg = lane >> 4;

  // T1: bijective XCD swizzle + column-major chunking (nwg % 8 == 0 for all our grids)
  const int GX = gridDim.x, GY = gridDim.y;
  int nwg = GX * GY;
  int orig = blockIdx.y * GX + blockIdx.x;
  int s = (orig & 7) * (nwg >> 3) + (orig >> 3);
  int bx = s / GY, by = s - bx * GY;
  const int bm = by * 256, bn = bx * 256;

  // split-K range
  const int z = blockIdx.z;
  int tilesK = K >> 6;
  int qs = tilesK / SPLITK, rs = tilesK - qs * SPLITK;
  int ntz = qs + (z < rs ? 1 : 0);
  int k0 = (z * qs + (z < rs ? z : rs)) << 6;

  f32x4 acc[8][4];
  #pragma unroll
  for (int i = 0; i < 8; i++)
    #pragma unroll
    for (int j = 0; j < 4; j++) acc[i][j] = (f32x4){0.f, 0.f, 0.f, 0.f};

  // hoisted per-thread staging pointers (advance +64 per staged tile; no per-tile mul)
  const int drw = tid >> 3;                       // dest row within half (0..63), s2=1 adds 64
  const int gsl8 = ((tid - drw) & 7) << 3;        // inverse-rotated source slot
  const u16* pA0 = A  + (size_t)(bm +       drw) * K + k0 + gsl8;
  const u16* pA1 = A  + (size_t)(bm + 128 + drw) * K + k0 + gsl8;
  const u16* pB0 = Bt + (size_t)(bn +       drw) * K + k0 + gsl8;
  const u16* pB1 = Bt + (size_t)(bn + 128 + drw) * K + k0 + gsl8;
  const size_t s2o = (size_t)64 * K;              // s2=1: dest rows +64
  const int dld = wid << 9;                       // dest: wid*512 elements (+4096 for s2=1)

  // stage all 4 half-tiles of one K-tile into dbuf d: 8 gl16/thread
  auto stageTile = [&](int d) {
    u16* dA0 = &sA[d][0][dld]; u16* dA1 = &sA[d][1][dld];
    u16* dB0 = &sB[d][0][dld]; u16* dB1 = &sB[d][1][dld];
    gl16(pA0, dA0); gl16(pA0 + s2o, dA0 + 4096);
    gl16(pB0, dB0); gl16(pB0 + s2o, dB0 + 4096);
    gl16(pA1, dA1); gl16(pA1 + s2o, dA1 + 4096);
    gl16(pB1, dB1); gl16(pB1 + s2o, dB1 + 4096);
    pA0 += 64; pA1 += 64; pB0 += 64; pB1 += 64;
  };

  // prologue: tiles 0 and 1 in flight (16 loads outstanding)
  stageTile(0);
  if (ntz > 1) stageTile(1);

  for (int t = 0; t < ntz; ++t) {
    int d = t & 1;
    if (t + 1 < ntz) asm volatile("s_waitcnt vmcnt(8)" ::: "memory");  // tile t landed; t+1 in flight
    else             asm volatile("s_waitcnt vmcnt(0)" ::: "memory");  // final tile
    __builtin_amdgcn_s_barrier();              // all waves: buf d ready
    QUAD(d, 0, 0);
    QUAD(d, 0, 1);
    QUAD(d, 1, 0);
    QUAD(d, 1, 1);
    __builtin_amdgcn_s_barrier();              // all waves done reading buf d
    __builtin_amdgcn_sched_barrier(0);
    if (t + 2 < ntz) stageTile(d);             // refill freed buffer with tile t+2
  }

  // epilogue
  #pragma unroll
  for (int ii = 0; ii < 8; ii++) {
    int row = bm + wr * 128 + ii * 16 + kg * 4;
    #pragma unroll
    for (int jj = 0; jj < 4; jj++) {
      int col = bn + wc * 64 + jj * 16 + r15;
      if (EPI == 4) {
        size_t zoff = (size_t)z * M * N;
        #pragma unroll
        for (int q2 = 0; q2 < 4; q2++)
          ((float*)out)[zoff + (size_t)(row + q2) * N + col] = acc[ii][jj][q2];
      } else {
        float bv = bias[col];
        #pragma unroll
        for (int q2 = 0; q2 < 4; q2++) {
          float v = acc[ii][jj][q2] + bv;
          if (EPI == 2) v = 0.5f * v * (1.0f + erff(v * 0.70710678118f));
          ((u16*)out)[(size_t)(row + q2) * N + col] = f2bf(v);
        }
      }
    }
  }
}

// ---------------- 128x128 counted-vmcnt GEMM (attn-dense) ----------------
// Same T2 slot-rotation + T4 counted scheme, 4 waves, 64KB LDS (2 blocks/CU).
// EPI 1: out = bf16(acc + bias + f32resid)
template<int EPI>
__global__ __launch_bounds__(256) void gemm_bt_k(const u16* __restrict__ A,
                                                 const u16* __restrict__ Bt,
                                                 const float* __restrict__ bias,
                                                 const void* __restrict__ resid,
                                                 u16* __restrict__ out,
                                                 int M, int N, int K) {
  __shared__ __align__(16) u16 As[2][128 * 64];
  __shared__ __align__(16) u16 Bs[2][128 * 64];
  const int tid = threadIdx.x;
  const int lane = tid & 63, wid = tid >> 6;
  const int wm = (wid >> 1) * 64, wn = (wid & 1) * 64;
  const int r15 = lane & 15, kg = lane >> 4;
  const int srow = lane >> 3;

  const int GX = gridDim.x, GY = gridDim.y;
  int nwg = GX * GY;
  int orig = blockIdx.y * GX + blockIdx.x;
  int s = (orig & 7) * (nwg >> 3) + (orig >> 3);
  int bx = s / GY, by = s - bx * GY;
  const int bm = by * 128, bn = bx * 128;

  f32x4 acc[4][4];
  #pragma unroll
  for (int i = 0; i < 4; i++)
    #pragma unroll
    for (int j = 0; j < 4; j++) acc[i][j] = (f32x4){0.f, 0.f, 0.f, 0.f};

  // hoisted staging pointers: chunk = (c<<2)|wid covers rows chunk*8..+8
  // dest slot = lane&7 -> source slot = (dslot - row)&7 (T2 inverse rotation)
  const u16* pAc[4]; const u16* pBc[4];
  #pragma unroll
  for (int c = 0; c < 4; c++) {
    int chunk = (c << 2) | wid;
    int row = (chunk << 3) + srow;
    int gsl = ((lane & 7) - row) & 7;
    pAc[c] = A  + (size_t)(bm + row) * K + (gsl << 3);
    pBc[c] = Bt + (size_t)(bn + row) * K + (gsl << 3);
  }
  auto STAGE = [&](int buf, int kt) {
    #pragma unroll
    for (int c = 0; c < 4; c++) {
      int chunk = (c << 2) | wid;
      gl16(pAc[c] + kt, &As[buf][chunk << 9]);
      gl16(pBc[c] + kt, &Bs[buf][chunk << 9]);
    }
  };
  auto COMPUTE = [&](int buf) {
    #pragma unroll
    for (int ks = 0; ks < 2; ks++) {
      bf16x8 af[4], bfr[4];
      #pragma unroll
      for (int i = 0; i < 4; i++) {
        int row = wm + i * 16 + r15;
        af[i] = *(const bf16x8*)&As[buf][row * 64 + (((ks << 2) + kg + row) & 7) * 8];
      }
      #pragma unroll
      for (int i = 0; i < 4; i++) {
        int row = wn + i * 16 + r15;
        bfr[i] = *(const bf16x8*)&Bs[buf][row * 64 + (((ks << 2) + kg + row) & 7) * 8];
      }
      #pragma unroll
      for (int i = 0; i < 4; i++)
        #pragma unroll
        for (int j = 0; j < 4; j++)
          acc[i][j] = mfma16(af[i], bfr[j], acc[i][j]);
    }
  };

  const int nt = K >> 6;
  STAGE(0, 0);
  if (nt > 1) STAGE(1, 64);
  for (int t = 0; t < nt; ++t) {
    if (t + 1 < nt) asm volatile("s_waitcnt vmcnt(8)" ::: "memory");
    else            asm volatile("s_waitcnt vmcnt(0)" ::: "memory");
    __builtin_amdgcn_s_barrier();
    COMPUTE(t & 1);
    __builtin_amdgcn_s_barrier();
    __builtin_amdgcn_sched_barrier(0);
    if (t + 2 < nt) STAGE(t & 1, (t + 2) << 6);
  }

  #pragma unroll
  for (int i = 0; i < 4; i++) {
    int row0 = bm + wm + i * 16 + kg * 4;
    #pragma unroll
    for (int j = 0; j < 4; j++) {
      int col = bn + wn + j * 16 + r15;
      float bv = bias[col];
      #pragma unroll
      for (int q2 = 0; q2 < 4; q2++) {
        int row = row0 + q2;
        float v = acc[i][j][q2] + bv;
        if (EPI == 1) v += ((const float*)resid)[(size_t)row * N + col];
        out[(size_t)row * N + col] = f2bf(v);
      }
    }
  }
}

// ---------------- fused attention: per (32-row q-block, head, batch) ----------------
__global__ __launch_bounds__(256) void attn_k(const u16* __restrict__ QKV,
                                              const float* __restrict__ mask,
                                              u16* __restrict__ ctx) {
  __shared__ __align__(16) u16 sQ[32 * 72];
  __shared__ __align__(16) u16 sK[64 * 72];
  __shared__ __align__(16) u16 sVt[64 * 72];
  __shared__ __align__(16) u16 sS[32 * 520];
  __shared__ float sSum[32];
  const int t = threadIdx.x, lane = t & 63, wid = t >> 6;
  const int qb = blockIdx.x, h = blockIdx.y, b = blockIdx.z;
  const int r15 = lane & 15, kg = lane >> 4;
  const int mg = wid >> 1, half = wid & 1;
  const size_t qoff = (size_t)h * 64;
  const size_t koff = 1024 + qoff, voff = 2048 + qoff;

  {  // stage Q block (32 x 64)
    int row = t >> 3, d0 = (t & 7) * 8;
    *(u16x8*)&sQ[row * 72 + d0] =
        *(const u16x8*)&QKV[((size_t)(b * 512 + qb * 32 + row)) * 3072 + qoff + d0];
  }

  for (int kt = 0; kt < 8; ++kt) {
    int row = t >> 2, d0 = (t & 3) * 16;
    const u16* src = &QKV[((size_t)(b * 512 + kt * 64 + row)) * 3072 + koff + d0];
    *(u16x8*)&sK[row * 72 + d0] = *(const u16x8*)src;
    *(u16x8*)&sK[row * 72 + d0 + 8] = *(const u16x8*)(src + 8);
    __syncthreads();
    bf16x8 qf0 = *(const bf16x8*)&sQ[(mg * 16 + r15) * 72 + kg * 8];
    bf16x8 qf1 = *(const bf16x8*)&sQ[(mg * 16 + r15) * 72 + 32 + kg * 8];
    #pragma unroll
    for (int n2 = 0; n2 < 2; n2++) {
      int nt = half * 2 + n2;
      f32x4 sacc = (f32x4){0.f, 0.f, 0.f, 0.f};
      sacc = mfma16(qf0, *(const bf16x8*)&sK[(nt * 16 + r15) * 72 + kg * 8], sacc);
      sacc = mfma16(qf1, *(const bf16x8*)&sK[(nt * 16 + r15) * 72 + 32 + kg * 8], sacc);
      int col = kt * 64 + nt * 16 + r15;
      float mv = mask[b * 512 + col];
      #pragma unroll
      for (int q = 0; q < 4; q++) {
        int rl = mg * 16 + kg * 4 + q;
        sS[rl * 520 + col] = f2bf(sacc[q] * 0.125f + mv);
      }
    }
    __syncthreads();
  }

  {
    int row = t >> 3, seg = t & 7;
    float mx = -1e30f;
    for (int j = 0; j < 64; j++)
      mx = fmaxf(mx, bf2f(sS[row * 520 + seg * 64 + j]));
    mx = fmaxf(mx, __shfl_xor(mx, 1));
    mx = fmaxf(mx, __shfl_xor(mx, 2));
    mx = fmaxf(mx, __shfl_xor(mx, 4));
    float sum = 0.f;
    for (int j = 0; j < 64; j++) {
      int idx = row * 520 + seg * 64 + j;
      float p = __expf(bf2f(sS[idx]) - mx);
      sum += p;
      sS[idx] = f2bf(p);
    }
    sum += __shfl_xor(sum, 1);
    sum += __shfl_xor(sum, 2);
    sum += __shfl_xor(sum, 4);
    if (seg == 0) sSum[row] = sum;
  }
  __syncthreads();

  f32x4 pacc[2];
  pacc[0] = (f32x4){0.f, 0.f, 0.f, 0.f};
  pacc[1] = (f32x4){0.f, 0.f, 0.f, 0.f};
  for (int vt = 0; vt < 8; ++vt) {
    int rowk = t >> 2, d0 = (t & 3) * 16;
    const u16* src = &QKV[((size_t)(b * 512 + vt * 64 + rowk)) * 3072 + voff + d0];
    u16x8 v0 = *(const u16x8*)src;
    u16x8 v1 = *(const u16x8*)(src + 8);
    #pragma unroll
    for (int e = 0; e < 8; e++) {
      sVt[(d0 + e) * 72 + rowk] = v0[e];
      sVt[(d0 + 8 + e) * 72 + rowk] = v1[e];
    }
    __syncthreads();
    bf16x8 pf0 = *(const bf16x8*)&sS[(mg * 16 + r15) * 520 + vt * 64 + kg * 8];
    bf16x8 pf1 = *(const bf16x8*)&sS[(mg * 16 + r15) * 520 + vt * 64 + 32 + kg * 8];
    #pragma unroll
    for (int n2 = 0; n2 < 2; n2++) {
      int dcol = half * 32 + n2 * 16;
      pacc[n2] = mfma16(pf0, *(const bf16x8*)&sVt[(dcol + r15) * 72 + kg * 8], pacc[n2]);
      pacc[n2] = mfma16(pf1, *(const bf16x8*)&sVt[(dcol + r15) * 72 + 32 + kg * 8], pacc[n2]);
    }
    __syncthreads();
  }
  #pragma unroll
  for (int n2 = 0; n2 < 2; n2++) {
    int d = half * 32 + n2 * 16 + r15;
    #pragma unroll
    for (int q = 0; q < 4; q++) {
      int rl = mg * 16 + kg * 4 + q;
      float v = pacc[n2][q] / sSum[rl];
      ctx[((size_t)(b * 512 + qb * 32 + rl)) * 1024 + qoff + d] = f2bf(v);
    }
  }
}

// ---------------- LayerNorm over rows of 1024 ----------------
template<int OUTF32>
__global__ __launch_bounds__(256) void ln_k(const u16* __restrict__ in,
                                            const float* __restrict__ g,
                                            const float* __restrict__ be,
                                            void* __restrict__ out) {
  int row = blockIdx.x, t = threadIdx.x;
  const u16* rp = in + (size_t)row * 1024 + t * 4;
  u16x4 raw = *(const u16x4*)rp;
  float x[4];
  #pragma unroll
  for (int i = 0; i < 4; i++) x[i] = bf2f(raw[i]);
  float s = x[0] + x[1] + x[2] + x[3];
  float q = x[0]*x[0] + x[1]*x[1] + x[2]*x[2] + x[3]*x[3];
  #pragma unroll
  for (int off = 32; off; off >>= 1) {
    s += __shfl_down(s, off);
    q += __shfl_down(q, off);
  }
  __shared__ float rs_[4], rq_[4];
  int wid = t >> 6, lane = t & 63;
  if (!lane) { rs_[wid] = s; rq_[wid] = q; }
  __syncthreads();
  float S1 = rs_[0] + rs_[1] + rs_[2] + rs_[3];
  float S2 = rq_[0] + rq_[1] + rq_[2] + rq_[3];
  float mu = S1 * (1.0f / 1024.0f);
  float inv = rsqrtf(S2 * (1.0f / 1024.0f) - mu * mu + 1e-5f);
  #pragma unroll
  for (int i = 0; i < 4; i++) {
    int c = t * 4 + i;
    float y = (x[i] - mu) * inv * g[c] + be[c];
    if (OUTF32) ((float*)out)[(size_t)row * 1024 + c] = y;
    else        ((u16*)out)[(size_t)row * 1024 + c] = f2bf(y);
  }
}

// ---------------- split-K reduce (3 partials) + bias + bf16 resid + LayerNorm -> fp32 ----------------
__global__ __launch_bounds__(256) void ln2r_k(const float* __restrict__ part,
                                              const float* __restrict__ bias,
                                              const u16* __restrict__ resid,
                                              const float* __restrict__ g,
                                              const float* __restrict__ be,
                                              float* __restrict__ out) {
  const int row = blockIdx.x, t = threadIdx.x;
  const size_t base = (size_t)row * 1024 + t * 4;
  float4 p0 = *(const float4*)(part + base);
  float4 p1 = *(const float4*)(part + 4194304 + base);
  float4 p2 = *(const float4*)(part + 8388608 + base);
  u16x4 rr = *(const u16x4*)(resid + base);
  float x[4];
  x[0] = p0.x + p1.x + p2.x + bias[t*4+0] + bf2f(rr[0]);
  x[1] = p0.y + p1.y + p2.y + bias[t*4+1] + bf2f(rr[1]);
  x[2] = p0.z + p1.z + p2.z + bias[t*4+2] + bf2f(rr[2]);
  x[3] = p0.w + p1.w + p2.w + bias[t*4+3] + bf2f(rr[3]);
  float s = x[0] + x[1] + x[2] + x[3];
  float q = x[0]*x[0] + x[1]*x[1] + x[2]*x[2] + x[3]*x[3];
  #pragma unroll
  for (int off = 32; off; off >>= 1) {
    s += __shfl_down(s, off);
    q += __shfl_down(q, off);
  }
  __shared__ float rs_[4], rq_[4];
  int wid = t >> 6, lane = t & 63;
  if (!lane) { rs_[wid] = s; rq_[wid] = q; }
  __syncthreads();
  float S1 = rs_[0] + rs_[1] + rs_[2] + rs_[3];
  float S2 = rq_[0] + rq_[1] + rq_[2] + rq_[3];
  float mu = S1 * (1.0f / 1024.0f);
  float inv = rsqrtf(S2 * (1.0f / 1024.0f) - mu * mu + 1e-5f);
  #pragma unroll
  for (int i = 0; i < 4; i++) {
    int c = t * 4 + i;
    out[(size_t)row * 1024 + c] = (x[i] - mu) * inv * g[c] + be[c];
  }
}

// ---------------- launch ----------------
extern "C" void kernel_launch(void* const* d_in, const int* in_sizes, int n_in,
                              void* d_out, int out_size, void* d_ws, size_t ws_size,
                              hipStream_t stream) {
  const float* hidden = (const float*)d_in[0];
  const float* mask   = (const float*)d_in[1];
  const float* wq  = (const float*)d_in[2];  const float* bq  = (const float*)d_in[3];
  const float* wk  = (const float*)d_in[4];  const float* bk  = (const float*)d_in[5];
  const float* wv  = (const float*)d_in[6];  const float* bv  = (const float*)d_in[7];
  const float* wo  = (const float*)d_in[8];  const float* bo  = (const float*)d_in[9];
  const float* ln1g = (const float*)d_in[10]; const float* ln1b = (const float*)d_in[11];
  const float* wi  = (const float*)d_in[12]; const float* bi  = (const float*)d_in[13];
  const float* wo2 = (const float*)d_in[14]; const float* bo2 = (const float*)d_in[15];
  const float* ln2g = (const float*)d_in[16]; const float* ln2b = (const float*)d_in[17];

  char* ws = (char*)d_ws;
  // layout (bytes). The front 56MB [WqkvT..AD] is all dead by FFN2 time and is
  // reused as the 48MB fp32 split-K partial buffer (3 x [4096][1024] fp32).
  u16*   WqkvT = (u16*)(ws + 0);                 //  6291456  [3072][1024] bf16
  u16*   WoT   = (u16*)(ws + 6291456);           //  2097152
  u16*   Xb    = (u16*)(ws + 8388608);           //  8388608  [4096][1024]
  u16*   QKVb  = (u16*)(ws + 16777216);          // 25165824  [4096][3072]
  u16*   Ctx   = (u16*)(ws + 41943040);          //  8388608
  u16*   AD    = (u16*)(ws + 50331648);          //  8388608
  float* part  = (float*)(ws + 0);               // 50331648  (overlaps dead region)
  u16*   AO    = (u16*)(ws + 58720256);          //  8388608
  u16*   Inter = (u16*)(ws + 67108864);          // 33554432  [4096][4096]
  u16*   WiT   = (u16*)(ws + 100663296);         //  8388608  [4096][1024]
  u16*   Wo2T  = (u16*)(ws + 109051904);         //  8388608  [1024][4096]
  float* bqkv  = (float*)(ws + 117440512);       //    12288

  cvt_bf16_k<<<2048, 256, 0, stream>>>(hidden, Xb, 4194304);
  tcvt_k<<<dim3(32, 32),  256, 0, stream>>>(wq,  WqkvT,                1024, 1024);
  tcvt_k<<<dim3(32, 32),  256, 0, stream>>>(wk,  WqkvT + 1024 * 1024,  1024, 1024);
  tcvt_k<<<dim3(32, 32),  256, 0, stream>>>(wv,  WqkvT + 2048 * 1024,  1024, 1024);
  tcvt_k<<<dim3(32, 32),  256, 0, stream>>>(wo,  WoT,  1024, 1024);
  tcvt_k<<<dim3(128, 32), 256, 0, stream>>>(wi,  WiT,  1024, 4096);
  tcvt_k<<<dim3(32, 128), 256, 0, stream>>>(wo2, Wo2T, 4096, 1024);
  pack_bias_k<<<12, 256, 0, stream>>>(bq, bk, bv, bqkv);

  // QKV projection: [4096,1024] @ [1024,3072]
  gemm8p_k<0, 1><<<dim3(12, 16, 1), 512, 0, stream>>>(Xb, WqkvT, bqkv, QKVb, 4096, 3072, 1024);

  attn_k<<<dim3(16, 16, 8), 256, 0, stream>>>(QKVb, mask, Ctx);

  // attn out-proj + f32 residual
  gemm_bt_k<1><<<dim3(8, 32), 256, 0, stream>>>(Ctx, WoT, bo, hidden, AD, 4096, 1024, 1024);
  ln_k<0><<<4096, 256, 0, stream>>>(AD, ln1g, ln1b, AO);

  // FFN1 + GELU: [4096,1024] @ [1024,4096]
  gemm8p_k<2, 1><<<dim3(16, 16, 1), 512, 0, stream>>>(AO, WiT, bi, Inter, 4096, 4096, 1024);

  // FFN2 split-K=3 partials: [4096,4096] @ [4096,1024]
  gemm8p_k<4, 3><<<dim3(4, 16, 3), 512, 0, stream>>>(Inter, Wo2T, nullptr, part, 4096, 1024, 4096);

  // reduce partials + bias + residual(AO) + LN2 -> fp32 out
  ln2r_k<<<4096, 256, 0, stream>>>(part, bo2, AO, ln2g, ln2b, (float*)d_out);
}

// Round 6
// 374.226 us; speedup vs baseline: 1.3121x; 1.1010x over previous
//
#include <hip/hip_runtime.h>
#include <math.h>

#define DI __device__ __forceinline__

typedef unsigned short u16;
typedef __attribute__((ext_vector_type(8))) u16 u16x8;
typedef __attribute__((ext_vector_type(4))) u16 u16x4;
typedef __attribute__((ext_vector_type(8))) __bf16 bf16x8;
typedef __attribute__((ext_vector_type(4))) float f32x4;

typedef const __attribute__((address_space(1))) unsigned int g_u32;
typedef __attribute__((address_space(3))) unsigned int l_u32;

DI float bf2f(u16 u) {
  unsigned v = ((unsigned)u) << 16;
  float f; __builtin_memcpy(&f, &v, 4); return f;
}
DI u16 f2bf(float f) {
  unsigned u; __builtin_memcpy(&u, &f, 4);
  u += 0x7fff + ((u >> 16) & 1);   // RNE
  return (u16)(u >> 16);
}
DI f32x4 mfma16(bf16x8 a, bf16x8 b, f32x4 c) {
  return __builtin_amdgcn_mfma_f32_16x16x32_bf16(a, b, c, 0, 0, 0);
}
DI void gl16(const void* g, const u16* lds) {   // async global->LDS, 16B/lane
  __builtin_amdgcn_global_load_lds((g_u32*)g, (l_u32*)lds, 16, 0, 0);
}
DI unsigned cvtpk(float lo, float hi) {         // 2 f32 -> packed bf16 pair
  unsigned d;
  asm("v_cvt_pk_bf16_f32 %0, %1, %2" : "=v"(d) : "v"(lo), "v"(hi));
  return d;
}

// ---------------- conversion: fp32 -> bf16 (elementwise) ----------------
__global__ __launch_bounds__(256) void cvt_bf16_k(const float* __restrict__ in,
                                                  u16* __restrict__ out, int n) {
  int i = (blockIdx.x * 256 + threadIdx.x) * 8;
  if (i >= n) return;
  float4 a = *(const float4*)(in + i);
  float4 b = *(const float4*)(in + i + 4);
  u16x8 o;
  o[0] = f2bf(a.x); o[1] = f2bf(a.y); o[2] = f2bf(a.z); o[3] = f2bf(a.w);
  o[4] = f2bf(b.x); o[5] = f2bf(b.y); o[6] = f2bf(b.z); o[7] = f2bf(b.w);
  *(u16x8*)(out + i) = o;
}

// ---------------- conversion: fp32 [K][N] -> bf16 [N][K] (transpose) ----------------
__global__ __launch_bounds__(256) void tcvt_k(const float* __restrict__ in,
                                              u16* __restrict__ out, int K, int N) {
  __shared__ float tile[32][33];
  int n0 = blockIdx.x * 32, k0 = blockIdx.y * 32;
  int tx = threadIdx.x & 31, ty = threadIdx.x >> 5;  // 32 x 8
  #pragma unroll
  for (int i = 0; i < 4; i++) {
    int kr = ty + i * 8;
    tile[kr][tx] = in[(size_t)(k0 + kr) * N + n0 + tx];
  }
  __syncthreads();
  #pragma unroll
  for (int i = 0; i < 4; i++) {
    int nr = ty + i * 8;
    out[(size_t)(n0 + nr) * K + k0 + tx] = f2bf(tile[tx][nr]);
  }
}

__global__ __launch_bounds__(256) void pack_bias_k(const float* __restrict__ b0,
                                                   const float* __restrict__ b1,
                                                   const float* __restrict__ b2,
                                                   float* __restrict__ out) {
  int i = blockIdx.x * 256 + threadIdx.x;   // grid 12 -> 3072
  float v = (i < 1024) ? b0[i] : (i < 2048 ? b1[i - 1024] : b2[i - 2048]);
  out[i] = v;
}

// ---------------- V -> V^T per head: QKVb V-part -> VT[bh][64 d][512 kpos] ----------------
__global__ __launch_bounds__(256) void vtr_k(const u16* __restrict__ QKV,
                                             u16* __restrict__ VT) {
  __shared__ u16 tile[64][72];
  const int t = threadIdx.x;
  const int kt = blockIdx.x, bh = blockIdx.y;      // 8 x 128
  const int b = bh >> 4, h = bh & 15;
  {
    int r = t >> 2, d0 = (t & 3) * 16;
    const u16* src = &QKV[((size_t)(b * 512 + kt * 64 + r)) * 3072 + 2048 + h * 64 + d0];
    *(u16x8*)&tile[r][d0] = *(const u16x8*)src;
    *(u16x8*)&tile[r][d0 + 8] = *(const u16x8*)(src + 8);
  }
  __syncthreads();
  int d = t >> 2, kseg = (t & 3) * 16;
  u16x8 o0, o1;
  #pragma unroll
  for (int j = 0; j < 8; j++) { o0[j] = tile[kseg + j][d]; o1[j] = tile[kseg + 8 + j][d]; }
  u16* dst = &VT[((size_t)bh << 15) + (size_t)d * 512 + kt * 64 + kseg];
  *(u16x8*)dst = o0;
  *(u16x8*)(dst + 8) = o1;
}

// ================= 256x256 8-phase GEMM (T1+T2+T3+T4+T5) =================
#define QUAD(d, mh, nh) do {                                                          \
  const u16* Ab_ = &sA[d][wr][0];                                                     \
  const u16* Bb_ = &sB[d][wc >> 1][0];                                                \
  bf16x8 af_[4][2], bv_[2][2];                                                        \
  _Pragma("unroll") for (int i_ = 0; i_ < 4; i_++) {                                  \
    int row_ = (mh) * 64 + i_ * 16 + r15;                                             \
    _Pragma("unroll") for (int ks_ = 0; ks_ < 2; ks_++)                               \
      af_[i_][ks_] = *(const bf16x8*)&Ab_[row_ * 64 + ((((ks_ << 2) | kg) + row_) & 7) * 8]; } \
  _Pragma("unroll") for (int j_ = 0; j_ < 2; j_++) {                                  \
    int row_ = (wc & 1) * 64 + (nh) * 32 + j_ * 16 + r15;                             \
    _Pragma("unroll") for (int ks_ = 0; ks_ < 2; ks_++)                               \
      bv_[j_][ks_] = *(const bf16x8*)&Bb_[row_ * 64 + ((((ks_ << 2) | kg) + row_) & 7) * 8]; } \
  __builtin_amdgcn_s_barrier();                                                       \
  __builtin_amdgcn_s_setprio(1);                                                      \
  _Pragma("unroll") for (int i_ = 0; i_ < 4; i_++)                                    \
    _Pragma("unroll") for (int j_ = 0; j_ < 2; j_++)                                  \
      _Pragma("unroll") for (int ks_ = 0; ks_ < 2; ks_++)                             \
        acc[(mh) * 4 + i_][(nh) * 2 + j_] =                                           \
            mfma16(af_[i_][ks_], bv_[j_][ks_], acc[(mh) * 4 + i_][(nh) * 2 + j_]);    \
  __builtin_amdgcn_s_setprio(0);                                                      \
} while (0)

template<int EPI, int SPLITK>
__global__ __launch_bounds__(512, 2) void gemm8p_k(const u16* __restrict__ A,
                                                   const u16* __restrict__ Bt,
                                                   const float* __restrict__ bias,
                                                   void* __restrict__ out,
                                                   int M, int N, int K) {
  __shared__ __align__(16) u16 sA[2][2][128 * 64];
  __shared__ __align__(16) u16 sB[2][2][128 * 64];
  const int tid = threadIdx.x;
  const int lane = tid & 63, wid = tid >> 6;
  const int wr = wid >> 2, wc = wid & 3;          // 2 x 4 waves
  const int r15 = lane & 15, kg = lane >> 4;

  const int GX = gridDim.x, GY = gridDim.y;
  int nwg = GX * GY;
  int orig = blockIdx.y * GX + blockIdx.x;
  int s = (orig & 7) * (nwg >> 3) + (orig >> 3);
  int bx = s / GY, by = s - bx * GY;
  const int bm = by * 256, bn = bx * 256;

  const int z = blockIdx.z;
  int tilesK = K >> 6;
  int qs = tilesK / SPLITK, rs = tilesK - qs * SPLITK;
  int ntz = qs + (z < rs ? 1 : 0);
  int k0 = (z * qs + (z < rs ? z : rs)) << 6;

  f32x4 acc[8][4];
  #pragma unroll
  for (int i = 0; i < 8; i++)
    #pragma unroll
    for (int j = 0; j < 4; j++) acc[i][j] = (f32x4){0.f, 0.f, 0.f, 0.f};

  const int drw = tid >> 3;
  const int gsl8 = ((tid - drw) & 7) << 3;
  const u16* pA0 = A  + (size_t)(bm +       drw) * K + k0 + gsl8;
  const u16* pA1 = A  + (size_t)(bm + 128 + drw) * K + k0 + gsl8;
  const u16* pB0 = Bt + (size_t)(bn +       drw) * K + k0 + gsl8;
  const u16* pB1 = Bt + (size_t)(bn + 128 + drw) * K + k0 + gsl8;
  const size_t s2o = (size_t)64 * K;
  const int dld = wid << 9;

  auto stageTile = [&](int d) {
    u16* dA0 = &sA[d][0][dld]; u16* dA1 = &sA[d][1][dld];
    u16* dB0 = &sB[d][0][dld]; u16* dB1 = &sB[d][1][dld];
    gl16(pA0, dA0); gl16(pA0 + s2o, dA0 + 4096);
    gl16(pB0, dB0); gl16(pB0 + s2o, dB0 + 4096);
    gl16(pA1, dA1); gl16(pA1 + s2o, dA1 + 4096);
    gl16(pB1, dB1); gl16(pB1 + s2o, dB1 + 4096);
    pA0 += 64; pA1 += 64; pB0 += 64; pB1 += 64;
  };

  stageTile(0);
  if (ntz > 1) stageTile(1);

  for (int t = 0; t < ntz; ++t) {
    int d = t & 1;
    if (t + 1 < ntz) asm volatile("s_waitcnt vmcnt(8)" ::: "memory");
    else             asm volatile("s_waitcnt vmcnt(0)" ::: "memory");
    __builtin_amdgcn_s_barrier();
    QUAD(d, 0, 0);
    QUAD(d, 0, 1);
    QUAD(d, 1, 0);
    QUAD(d, 1, 1);
    __builtin_amdgcn_s_barrier();
    __builtin_amdgcn_sched_barrier(0);
    if (t + 2 < ntz) stageTile(d);
  }

  #pragma unroll
  for (int ii = 0; ii < 8; ii++) {
    int row = bm + wr * 128 + ii * 16 + kg * 4;
    #pragma unroll
    for (int jj = 0; jj < 4; jj++) {
      int col = bn + wc * 64 + jj * 16 + r15;
      if (EPI == 4) {
        size_t zoff = (size_t)z * M * N;
        #pragma unroll
        for (int q2 = 0; q2 < 4; q2++)
          ((float*)out)[zoff + (size_t)(row + q2) * N + col] = acc[ii][jj][q2];
      } else {
        float bv = bias[col];
        #pragma unroll
        for (int q2 = 0; q2 < 4; q2++) {
          float v = acc[ii][jj][q2] + bv;
          if (EPI == 2) v = 0.5f * v * (1.0f + erff(v * 0.70710678118f));
          ((u16*)out)[(size_t)(row + q2) * N + col] = f2bf(v);
        }
      }
    }
  }
}

// ---------------- 128x128 counted-vmcnt GEMM (attn-dense) ----------------
template<int EPI>
__global__ __launch_bounds__(256) void gemm_bt_k(const u16* __restrict__ A,
                                                 const u16* __restrict__ Bt,
                                                 const float* __restrict__ bias,
                                                 const void* __restrict__ resid,
                                                 u16* __restrict__ out,
                                                 int M, int N, int K) {
  __shared__ __align__(16) u16 As[2][128 * 64];
  __shared__ __align__(16) u16 Bs[2][128 * 64];
  const int tid = threadIdx.x;
  const int lane = tid & 63, wid = tid >> 6;
  const int wm = (wid >> 1) * 64, wn = (wid & 1) * 64;
  const int r15 = lane & 15, kg = lane >> 4;
  const int srow = lane >> 3;

  const int GX = gridDim.x, GY = gridDim.y;
  int nwg = GX * GY;
  int orig = blockIdx.y * GX + blockIdx.x;
  int s = (orig & 7) * (nwg >> 3) + (orig >> 3);
  int bx = s / GY, by = s - bx * GY;
  const int bm = by * 128, bn = bx * 128;

  f32x4 acc[4][4];
  #pragma unroll
  for (int i = 0; i < 4; i++)
    #pragma unroll
    for (int j = 0; j < 4; j++) acc[i][j] = (f32x4){0.f, 0.f, 0.f, 0.f};

  const u16* pAc[4]; const u16* pBc[4];
  #pragma unroll
  for (int c = 0; c < 4; c++) {
    int chunk = (c << 2) | wid;
    int row = (chunk << 3) + srow;
    int gsl = ((lane & 7) - row) & 7;
    pAc[c] = A  + (size_t)(bm + row) * K + (gsl << 3);
    pBc[c] = Bt + (size_t)(bn + row) * K + (gsl << 3);
  }
  auto STAGE = [&](int buf, int kt) {
    #pragma unroll
    for (int c = 0; c < 4; c++) {
      int chunk = (c << 2) | wid;
      gl16(pAc[c] + kt, &As[buf][chunk << 9]);
      gl16(pBc[c] + kt, &Bs[buf][chunk << 9]);
    }
  };
  auto COMPUTE = [&](int buf) {
    #pragma unroll
    for (int ks = 0; ks < 2; ks++) {
      bf16x8 af[4], bfr[4];
      #pragma unroll
      for (int i = 0; i < 4; i++) {
        int row = wm + i * 16 + r15;
        af[i] = *(const bf16x8*)&As[buf][row * 64 + (((ks << 2) + kg + row) & 7) * 8];
      }
      #pragma unroll
      for (int i = 0; i < 4; i++) {
        int row = wn + i * 16 + r15;
        bfr[i] = *(const bf16x8*)&Bs[buf][row * 64 + (((ks << 2) + kg + row) & 7) * 8];
      }
      #pragma unroll
      for (int i = 0; i < 4; i++)
        #pragma unroll
        for (int j = 0; j < 4; j++)
          acc[i][j] = mfma16(af[i], bfr[j], acc[i][j]);
    }
  };

  const int nt = K >> 6;
  STAGE(0, 0);
  if (nt > 1) STAGE(1, 64);
  for (int t = 0; t < nt; ++t) {
    if (t + 1 < nt) asm volatile("s_waitcnt vmcnt(8)" ::: "memory");
    else            asm volatile("s_waitcnt vmcnt(0)" ::: "memory");
    __builtin_amdgcn_s_barrier();
    COMPUTE(t & 1);
    __builtin_amdgcn_s_barrier();
    __builtin_amdgcn_sched_barrier(0);
    if (t + 2 < nt) STAGE(t & 1, (t + 2) << 6);
  }

  #pragma unroll
  for (int i = 0; i < 4; i++) {
    int row0 = bm + wm + i * 16 + kg * 4;
    #pragma unroll
    for (int j = 0; j < 4; j++) {
      int col = bn + wn + j * 16 + r15;
      float bv = bias[col];
      #pragma unroll
      for (int q2 = 0; q2 < 4; q2++) {
        int row = row0 + q2;
        float v = acc[i][j][q2] + bv;
        if (EPI == 1) v += ((const float*)resid)[(size_t)row * N + col];
        out[(size_t)row * N + col] = f2bf(v);
      }
    }
  }
}

// ================= flash attention: swapped QK^T, in-register softmax =================
// Grid (4 qb, 16 h, 8 b), 256 thr (4 waves x 32 q-rows). K and V^T tiles (64x64)
// double-buffered in LDS with slot-rotation swizzle, staged via global_load_lds,
// counted vmcnt(4). P held in registers (S^T layout: q = lane&15, k = k16*16+4g+reg);
// PV A-fragment built with v_cvt_pk_bf16_f32 + ds_bpermute 4-group exchange.
__global__ __launch_bounds__(256) void fattn_k(const u16* __restrict__ QKV,
                                               const u16* __restrict__ VT,
                                               const float* __restrict__ mask,
                                               u16* __restrict__ ctx) {
  __shared__ __align__(16) u16 sK[2][64 * 64];
  __shared__ __align__(16) u16 sV[2][64 * 64];
  __shared__ float sMask[512];
  const int t = threadIdx.x, lane = t & 63, wid = t >> 6;
  const int q15 = lane & 15, g = lane >> 4;
  const int qb = blockIdx.x, h = blockIdx.y, b = blockIdx.z;
  const int bh = b * 16 + h;
  const int qrow0 = qb * 128 + wid * 32;

  if (t < 128) *(float4*)&sMask[t * 4] = *(const float4*)&mask[b * 512 + t * 4];

  // Q fragments (B-operand): lane q15 = q-row, g*8 = d-octet
  bf16x8 qf[2][2];
  #pragma unroll
  for (int qt = 0; qt < 2; qt++)
    #pragma unroll
    for (int c = 0; c < 2; c++)
      qf[qt][c] = *(const bf16x8*)&QKV[(size_t)(b * 512 + qrow0 + qt * 16 + q15) * 3072 +
                                       h * 64 + c * 32 + g * 8];

  // staging pointers (slot-rotated source, linear LDS dest)
  const int srow0 = t >> 3;            // s2=0 row; s2=1 adds 32
  const int ssl = (((t & 7) - (t >> 3)) & 7) << 3;
  const u16* pK = QKV + (size_t)(b * 512 + srow0) * 3072 + 1024 + h * 64 + ssl;
  const u16* pV = VT + ((size_t)bh << 15) + (size_t)srow0 * 512 + ssl;
  const size_t kS2 = (size_t)32 * 3072;   // K rows +32
  const size_t vS2 = (size_t)32 * 512;    // V^T rows +32
  const int dld = t * 8;

  auto stage = [&](int d) {
    gl16(pK, &sK[d][dld]); gl16(pK + kS2, &sK[d][dld + 2048]);
    gl16(pV, &sV[d][dld]); gl16(pV + vS2, &sV[d][dld + 2048]);
    pK += 64 * 3072; pV += 64;
  };

  stage(0); stage(1);

  float m_[2] = {-1e30f, -1e30f}, l_[2] = {0.f, 0.f};
  f32x4 oacc[2][4];
  #pragma unroll
  for (int qt = 0; qt < 2; qt++)
    #pragma unroll
    for (int dt = 0; dt < 4; dt++) oacc[qt][dt] = (f32x4){0.f, 0.f, 0.f, 0.f};

  const int bp0 = ((g & 1) * 32 + q15) * 4;    // ds_bpermute byte addr, src group 2*(g&1)
  const int bp1 = bp0 + 64;                     // src group 2*(g&1)+1

  for (int kt = 0; kt < 8; ++kt) {
    const int d = kt & 1;
    if (kt < 7) asm volatile("s_waitcnt vmcnt(4)" ::: "memory");
    else        asm volatile("s_waitcnt vmcnt(0)" ::: "memory");
    __builtin_amdgcn_s_barrier();

    // ---- QK^T (swapped: A=K rows, B=Q) -> lane holds P[q=q15][k=k16*16+4g+reg] ----
    f32x4 sc[2][4];
    #pragma unroll
    for (int qt = 0; qt < 2; qt++)
      #pragma unroll
      for (int k16 = 0; k16 < 4; k16++) sc[qt][k16] = (f32x4){0.f, 0.f, 0.f, 0.f};
    #pragma unroll
    for (int k16 = 0; k16 < 4; k16++) {
      int row = k16 * 16 + q15;
      bf16x8 ak0 = *(const bf16x8*)&sK[d][row * 64 + ((g + row) & 7) * 8];
      bf16x8 ak1 = *(const bf16x8*)&sK[d][row * 64 + ((4 + g + row) & 7) * 8];
      #pragma unroll
      for (int qt = 0; qt < 2; qt++) {
        sc[qt][k16] = mfma16(ak0, qf[qt][0], sc[qt][k16]);
        sc[qt][k16] = mfma16(ak1, qf[qt][1], sc[qt][k16]);
      }
    }

    // ---- scale + mask ----
    float mk[4][4];
    #pragma unroll
    for (int k16 = 0; k16 < 4; k16++)
      #pragma unroll
      for (int r = 0; r < 4; r++)
        mk[k16][r] = sMask[kt * 64 + k16 * 16 + g * 4 + r];
    float p[2][16];
    #pragma unroll
    for (int qt = 0; qt < 2; qt++)
      #pragma unroll
      for (int k16 = 0; k16 < 4; k16++)
        #pragma unroll
        for (int r = 0; r < 4; r++)
          p[qt][k16 * 4 + r] = sc[qt][k16][r] * 0.125f + mk[k16][r];

    // ---- online softmax (per q-column q15) + PV ----
    #pragma unroll
    for (int qt = 0; qt < 2; qt++) {
      float tmax = p[qt][0];
      #pragma unroll
      for (int j = 1; j < 16; j++) tmax = fmaxf(tmax, p[qt][j]);
      tmax = fmaxf(tmax, __shfl_xor(tmax, 16));
      tmax = fmaxf(tmax, __shfl_xor(tmax, 32));
      float mn = fmaxf(m_[qt], tmax);
      float al = __expf(m_[qt] - mn);
      m_[qt] = mn;
      float ts = 0.f;
      #pragma unroll
      for (int j = 0; j < 16; j++) { p[qt][j] = __expf(p[qt][j] - mn); ts += p[qt][j]; }
      ts += __shfl_xor(ts, 16);
      ts += __shfl_xor(ts, 32);
      l_[qt] = l_[qt] * al + ts;
      // rescale O (O-lane rows q' = g*4+reg -> fetch alpha from lane q')
      #pragma unroll
      for (int r = 0; r < 4; r++) {
        float alq = __shfl(al, g * 4 + r);
        #pragma unroll
        for (int dt = 0; dt < 4; dt++) oacc[qt][dt][r] *= alq;
      }
    }

    // pack P -> bf16 dwords: dwp[qt][k16][pp] covers k = k16*16 + 4g + 2pp+{0,1}
    unsigned dwp[2][4][2];
    #pragma unroll
    for (int qt = 0; qt < 2; qt++)
      #pragma unroll
      for (int k16 = 0; k16 < 4; k16++) {
        dwp[qt][k16][0] = cvtpk(p[qt][k16 * 4 + 0], p[qt][k16 * 4 + 1]);
        dwp[qt][k16][1] = cvtpk(p[qt][k16 * 4 + 2], p[qt][k16 * 4 + 3]);
      }

    // ---- PV: A-frag via bpermute exchange; B-frag = V^T rows from LDS ----
    #pragma unroll
    for (int cp = 0; cp < 2; cp++) {       // k-chunk of 32
      bf16x8 pa[2];
      #pragma unroll
      for (int qt = 0; qt < 2; qt++) {
        union { unsigned u[4]; bf16x8 v; } pu;
        #pragma unroll
        for (int pp = 0; pp < 2; pp++) {
          unsigned a0 = __builtin_amdgcn_ds_bpermute(bp0, (int)dwp[qt][2 * cp][pp]);
          unsigned b0 = __builtin_amdgcn_ds_bpermute(bp0, (int)dwp[qt][2 * cp + 1][pp]);
          unsigned a1 = __builtin_amdgcn_ds_bpermute(bp1, (int)dwp[qt][2 * cp][pp]);
          unsigned b1 = __builtin_amdgcn_ds_bpermute(bp1, (int)dwp[qt][2 * cp + 1][pp]);
          pu.u[pp] = (g & 2) ? b0 : a0;
          pu.u[2 + pp] = (g & 2) ? b1 : a1;
        }
        pa[qt] = pu.v;
      }
      #pragma unroll
      for (int dt = 0; dt < 4; dt++) {
        int row = dt * 16 + q15;
        bf16x8 vf = *(const bf16x8*)&sV[d][row * 64 + (((cp << 2) + g + row) & 7) * 8];
        oacc[0][dt] = mfma16(pa[0], vf, oacc[0][dt]);
        oacc[1][dt] = mfma16(pa[1], vf, oacc[1][dt]);
      }
    }

    __builtin_amdgcn_s_barrier();
    __builtin_amdgcn_sched_barrier(0);
    if (kt + 2 < 8) stage(d);
  }

  // ---- normalize + write ctx ----
  #pragma unroll
  for (int qt = 0; qt < 2; qt++) {
    float linv[4];
    #pragma unroll
    for (int r = 0; r < 4; r++) linv[r] = 1.0f / __shfl(l_[qt], g * 4 + r);
    #pragma unroll
    for (int dt = 0; dt < 4; dt++)
      #pragma unroll
      for (int r = 0; r < 4; r++) {
        int row = qrow0 + qt * 16 + g * 4 + r;
        ctx[(size_t)(b * 512 + row) * 1024 + h * 64 + dt * 16 + q15] =
            f2bf(oacc[qt][dt][r] * linv[r]);
      }
  }
}

// ---------------- LayerNorm over rows of 1024 ----------------
template<int OUTF32>
__global__ __launch_bounds__(256) void ln_k(const u16* __restrict__ in,
                                            const float* __restrict__ g,
                                            const float* __restrict__ be,
                                            void* __restrict__ out) {
  int row = blockIdx.x, t = threadIdx.x;
  const u16* rp = in + (size_t)row * 1024 + t * 4;
  u16x4 raw = *(const u16x4*)rp;
  float x[4];
  #pragma unroll
  for (int i = 0; i < 4; i++) x[i] = bf2f(raw[i]);
  float s = x[0] + x[1] + x[2] + x[3];
  float q = x[0]*x[0] + x[1]*x[1] + x[2]*x[2] + x[3]*x[3];
  #pragma unroll
  for (int off = 32; off; off >>= 1) {
    s += __shfl_down(s, off);
    q += __shfl_down(q, off);
  }
  __shared__ float rs_[4], rq_[4];
  int wid = t >> 6, lane = t & 63;
  if (!lane) { rs_[wid] = s; rq_[wid] = q; }
  __syncthreads();
  float S1 = rs_[0] + rs_[1] + rs_[2] + rs_[3];
  float S2 = rq_[0] + rq_[1] + rq_[2] + rq_[3];
  float mu = S1 * (1.0f / 1024.0f);
  float inv = rsqrtf(S2 * (1.0f / 1024.0f) - mu * mu + 1e-5f);
  #pragma unroll
  for (int i = 0; i < 4; i++) {
    int c = t * 4 + i;
    float y = (x[i] - mu) * inv * g[c] + be[c];
    if (OUTF32) ((float*)out)[(size_t)row * 1024 + c] = y;
    else        ((u16*)out)[(size_t)row * 1024 + c] = f2bf(y);
  }
}

// ---------------- split-K reduce (3 partials) + bias + bf16 resid + LayerNorm -> fp32 ----------------
__global__ __launch_bounds__(256) void ln2r_k(const float* __restrict__ part,
                                              const float* __restrict__ bias,
                                              const u16* __restrict__ resid,
                                              const float* __restrict__ g,
                                              const float* __restrict__ be,
                                              float* __restrict__ out) {
  const int row = blockIdx.x, t = threadIdx.x;
  const size_t base = (size_t)row * 1024 + t * 4;
  float4 p0 = *(const float4*)(part + base);
  float4 p1 = *(const float4*)(part + 4194304 + base);
  float4 p2 = *(const float4*)(part + 8388608 + base);
  u16x4 rr = *(const u16x4*)(resid + base);
  float x[4];
  x[0] = p0.x + p1.x + p2.x + bias[t*4+0] + bf2f(rr[0]);
  x[1] = p0.y + p1.y + p2.y + bias[t*4+1] + bf2f(rr[1]);
  x[2] = p0.z + p1.z + p2.z + bias[t*4+2] + bf2f(rr[2]);
  x[3] = p0.w + p1.w + p2.w + bias[t*4+3] + bf2f(rr[3]);
  float s = x[0] + x[1] + x[2] + x[3];
  float q = x[0]*x[0] + x[1]*x[1] + x[2]*x[2] + x[3]*x[3];
  #pragma unroll
  for (int off = 32; off; off >>= 1) {
    s += __shfl_down(s, off);
    q += __shfl_down(q, off);
  }
  __shared__ float rs_[4], rq_[4];
  int wid = t >> 6, lane = t & 63;
  if (!lane) { rs_[wid] = s; rq_[wid] = q; }
  __syncthreads();
  float S1 = rs_[0] + rs_[1] + rs_[2] + rs_[3];
  float S2 = rq_[0] + rq_[1] + rq_[2] + rq_[3];
  float mu = S1 * (1.0f / 1024.0f);
  float inv = rsqrtf(S2 * (1.0f / 1024.0f) - mu * mu + 1e-5f);
  #pragma unroll
  for (int i = 0; i < 4; i++) {
    int c = t * 4 + i;
    out[(size_t)row * 1024 + c] = (x[i] - mu) * inv * g[c] + be[c];
  }
}

// ---------------- launch ----------------
extern "C" void kernel_launch(void* const* d_in, const int* in_sizes, int n_in,
                              void* d_out, int out_size, void* d_ws, size_t ws_size,
                              hipStream_t stream) {
  const float* hidden = (const float*)d_in[0];
  const float* mask   = (const float*)d_in[1];
  const float* wq  = (const float*)d_in[2];  const float* bq  = (const float*)d_in[3];
  const float* wk  = (const float*)d_in[4];  const float* bk  = (const float*)d_in[5];
  const float* wv  = (const float*)d_in[6];  const float* bv  = (const float*)d_in[7];
  const float* wo  = (const float*)d_in[8];  const float* bo  = (const float*)d_in[9];
  const float* ln1g = (const float*)d_in[10]; const float* ln1b = (const float*)d_in[11];
  const float* wi  = (const float*)d_in[12]; const float* bi  = (const float*)d_in[13];
  const float* wo2 = (const float*)d_in[14]; const float* bo2 = (const float*)d_in[15];
  const float* ln2g = (const float*)d_in[16]; const float* ln2b = (const float*)d_in[17];

  char* ws = (char*)d_ws;
  u16*   WqkvT = (u16*)(ws + 0);                 //  6291456  [3072][1024] bf16
  u16*   WoT   = (u16*)(ws + 6291456);           //  2097152
  u16*   Xb    = (u16*)(ws + 8388608);           //  8388608  [4096][1024] (dead after QKV gemm)
  u16*   VTb   = (u16*)(ws + 8388608);           //  8388608  [128 bh][64][512] (reuses Xb slot)
  u16*   QKVb  = (u16*)(ws + 16777216);          // 25165824  [4096][3072]
  u16*   Ctx   = (u16*)(ws + 41943040);          //  8388608
  u16*   AD    = (u16*)(ws + 50331648);          //  8388608
  float* part  = (float*)(ws + 0);               // 50331648  (overlaps dead region at FFN2 time)
  u16*   AO    = (u16*)(ws + 58720256);          //  8388608
  u16*   Inter = (u16*)(ws + 67108864);          // 33554432  [4096][4096]
  u16*   WiT   = (u16*)(ws + 100663296);         //  8388608  [4096][1024]
  u16*   Wo2T  = (u16*)(ws + 109051904);         //  8388608  [1024][4096]
  float* bqkv  = (float*)(ws + 117440512);       //    12288

  cvt_bf16_k<<<2048, 256, 0, stream>>>(hidden, Xb, 4194304);
  tcvt_k<<<dim3(32, 32),  256, 0, stream>>>(wq,  WqkvT,                1024, 1024);
  tcvt_k<<<dim3(32, 32),  256, 0, stream>>>(wk,  WqkvT + 1024 * 1024,  1024, 1024);
  tcvt_k<<<dim3(32, 32),  256, 0, stream>>>(wv,  WqkvT + 2048 * 1024,  1024, 1024);
  tcvt_k<<<dim3(32, 32),  256, 0, stream>>>(wo,  WoT,  1024, 1024);
  tcvt_k<<<dim3(128, 32), 256, 0, stream>>>(wi,  WiT,  1024, 4096);
  tcvt_k<<<dim3(32, 128), 256, 0, stream>>>(wo2, Wo2T, 4096, 1024);
  pack_bias_k<<<12, 256, 0, stream>>>(bq, bk, bv, bqkv);

  // QKV projection: [4096,1024] @ [1024,3072]
  gemm8p_k<0, 1><<<dim3(12, 16, 1), 512, 0, stream>>>(Xb, WqkvT, bqkv, QKVb, 4096, 3072, 1024);

  // V -> V^T per head (into dead Xb slot)
  vtr_k<<<dim3(8, 128), 256, 0, stream>>>(QKVb, VTb);

  // flash attention
  fattn_k<<<dim3(4, 16, 8), 256, 0, stream>>>(QKVb, VTb, mask, Ctx);

  // attn out-proj + f32 residual
  gemm_bt_k<1><<<dim3(8, 32), 256, 0, stream>>>(Ctx, WoT, bo, hidden, AD, 4096, 1024, 1024);
  ln_k<0><<<4096, 256, 0, stream>>>(AD, ln1g, ln1b, AO);

  // FFN1 + GELU: [4096,1024] @ [1024,4096]
  gemm8p_k<2, 1><<<dim3(16, 16, 1), 512, 0, stream>>>(AO, WiT, bi, Inter, 4096, 4096, 1024);

  // FFN2 split-K=3 partials: [4096,4096] @ [4096,1024]
  gemm8p_k<4, 3><<<dim3(4, 16, 3), 512, 0, stream>>>(Inter, Wo2T, nullptr, part, 4096, 1024, 4096);

  // reduce partials + bias + residual(AO) + LN2 -> fp32 out
  ln2r_k<<<4096, 256, 0, stream>>>(part, bo2, AO, ln2g, ln2b, (float*)d_out);
}